// Round 5
// baseline (1142.512 us; speedup 1.0000x reference)
//
#include <hip/hip_runtime.h>
#include <math.h>

// Problem constants: B=32, T=64, I=E=Ha=Hb=256, O=1, P=T-1=63
#define B_   32
#define T_   64
#define P_   63
#define E_   256
#define G3_  768

typedef _Float16 half8 __attribute__((ext_vector_type(8)));
typedef _Float16 half4 __attribute__((ext_vector_type(4)));
typedef float    f32x4 __attribute__((ext_vector_type(4)));

__device__ __forceinline__ float sigmoidf_(float x) { return 1.0f / (1.0f + __expf(-x)); }
__device__ __forceinline__ float tanhfast_(float x) { float e = __expf(2.0f*x); return 1.0f - 2.0f/(e + 1.0f); }

// Barrier WITHOUT vmcnt drain: only LDS ops must be visible across it.
// Global loads/stores keep flowing across steps (counted vmcnt inserted by compiler at use).
__device__ __forceinline__ void barrier_lds_() {
    asm volatile("" ::: "memory");
    asm volatile("s_waitcnt lgkmcnt(0)" ::: "memory");
    __builtin_amdgcn_s_barrier();
    asm volatile("" ::: "memory");
}

// ---------------------------------------------------------------- K0: M[e,i] = out_w0[e]*emb_w[e,i]
__global__ __launch_bounds__(256) void k_prep(const float* __restrict__ emb_w,
                                              const float* __restrict__ out_w,
                                              float* __restrict__ Mmat) {
    int e = blockIdx.x, i = threadIdx.x;
    Mmat[(size_t)e * 256 + i] = out_w[e] * emb_w[(size_t)e * 256 + i];
}

// ---------------------------------------------------------------- K1: emb[t,b,e] = emb_w @ x[b,t,:] + emb_b
__global__ __launch_bounds__(256) void k_emb(const float* __restrict__ x,
                                             const float* __restrict__ emb_w,
                                             const float* __restrict__ emb_b,
                                             float* __restrict__ emb) {
    int t = blockIdx.x >> 5, b = blockIdx.x & 31;
    int tid = threadIdx.x;
    __shared__ float xr[E_];
    xr[tid] = x[((size_t)b * T_ + t) * E_ + tid];
    __syncthreads();
    const float* wr = emb_w + (size_t)tid * E_;
    float acc = emb_b[tid];
    for (int c = 0; c < 256; c += 4) {
        float4 wv = *reinterpret_cast<const float4*>(wr + c);
        float4 xv = *reinterpret_cast<const float4*>(&xr[c]);
        acc += wv.x * xv.x + wv.y * xv.y + wv.z * xv.z + wv.w * xv.w;
    }
    emb[((size_t)t * B_ + b) * E_ + tid] = acc;
}

// ---------------------------------------------------------------- K2: input gates -> fp16, transposed [o][r]
// b_ih folded always; b_hh folded for r,z gates only (n-gate's b_hh enters inside r*).
__global__ __launch_bounds__(256) void k_gates(const float* __restrict__ emb,
                                               const float* __restrict__ awih, const float* __restrict__ abih,
                                               const float* __restrict__ abhh,
                                               const float* __restrict__ bwih, const float* __restrict__ bbih,
                                               const float* __restrict__ bbhh,
                                               _Float16* __restrict__ giTa, _Float16* __restrict__ giTb) {
    int r0 = blockIdx.x * 8;
    int tid = threadIdx.x;
    __shared__ float es[8][E_];
    for (int rr = 0; rr < 8; ++rr) es[rr][tid] = emb[(size_t)(r0 + rr) * E_ + tid];
    __syncthreads();
    for (int gs = 0; gs < 6; ++gs) {
        const float* W    = (gs < 3) ? awih : bwih;
        const float* bih  = (gs < 3) ? abih : bbih;
        const float* bhh  = (gs < 3) ? abhh : bbhh;
        _Float16* giT     = (gs < 3) ? giTa : giTb;
        int gate = gs % 3;
        int grow = gate * 256 + tid;
        const float* wr = W + (size_t)grow * E_;
        float acc[8];
        #pragma unroll
        for (int rr = 0; rr < 8; ++rr) acc[rr] = 0.f;
        for (int c = 0; c < 256; c += 4) {
            float4 wv = *reinterpret_cast<const float4*>(wr + c);
            #pragma unroll
            for (int rr = 0; rr < 8; ++rr) {
                float4 ev = *reinterpret_cast<const float4*>(&es[rr][c]);
                acc[rr] += wv.x * ev.x + wv.y * ev.y + wv.z * ev.z + wv.w * ev.w;
            }
        }
        float bv = bih[grow] + ((gate < 2) ? bhh[grow] : 0.f);
        _Float16* dst = giT + (size_t)grow * 2048 + r0;
        #pragma unroll
        for (int rr = 0; rr < 8; ++rr) dst[rr] = (_Float16)(acc[rr] + bv);
    }
}

// ---------------------------------------------------------------- K2b: W_hh -> fp16 MFMA A-fragments
// wf[((ot*8+kc)*64 + lane)*8 + j] = (fp16) whh[ot*16 + (lane&15)][kc*32 + (lane>>4)*8 + j]
__global__ __launch_bounds__(64) void k_wfrag(const float* __restrict__ whh, _Float16* __restrict__ wf) {
    int ot = blockIdx.x >> 3, kc = blockIdx.x & 7, l = threadIdx.x;
    int orow = ot * 16 + (l & 15);
    int c0   = kc * 32 + (l >> 4) * 8;
    half8 v;
    #pragma unroll
    for (int j = 0; j < 8; ++j) v[j] = (_Float16)whh[(size_t)orow * 256 + c0 + j];
    *reinterpret_cast<half8*>(&wf[((size_t)(ot * 8 + kc) * 64 + l) * 8]) = v;
}

// ---------------------------------------------------------------- K2c: pack gi into per-(t,wave,chunk,lane) order.
// chunk c=g3*2+dt (6 chunks of 8: e=rt*4+j). gp[((t*8+w)*6 + c)*512 + l*8 + e]
__global__ __launch_bounds__(512) void k_gipack(const _Float16* __restrict__ gA, const _Float16* __restrict__ gB,
                                                _Float16* __restrict__ pA, _Float16* __restrict__ pB) {
    int g = blockIdx.x >> 6, t = blockIdx.x & 63;
    const _Float16* src = g ? gB : gA;
    _Float16*       dst = g ? pB : pA;
    int tid = threadIdx.x, w = tid >> 6, l = tid & 63, lg = l >> 4, lr = l & 15;
    #pragma unroll
    for (int c = 0; c < 6; ++c) {
        int g3 = c >> 1, dt = c & 1;
        half8 v;
        #pragma unroll
        for (int e = 0; e < 8; ++e) {
            int rt = e >> 2, j = e & 3;
            v[e] = src[(size_t)(g3 * 256 + w * 32 + dt * 16 + lg * 4 + j) * 2048 + t * 32 + rt * 16 + lr];
        }
        *reinterpret_cast<half8*>(&dst[((size_t)(t * 8 + w) * 6 + c) * 512 + l * 8]) = v;
    }
}

// ---------------------------------------------------------------- K3: triangular GRU chains, MFMA fp16.
// block=(g,p): 126 blocks x 512 threads. h fp32 in regs, fp16 copy in double-buffered
// swizzled LDS. W streamed through an explicit 4-deep REGISTER ring (afr): consume slot
// kc&3, reissue it for (kc+4)&7 — W is step-invariant so the ring wraps seamlessly across
// the lgkm-only barrier; every W load has >=4 kc + nonlin of latency cover. wfp pointers
// are made opaque per step (empty asm) so the compiler can't hoist/CSE the 48 loads.
__global__ __launch_bounds__(512, 2) void k_gru_f(
    const _Float16* __restrict__ gpa, const _Float16* __restrict__ gpb,
    const _Float16* __restrict__ wfa, const _Float16* __restrict__ wfb,
    const float* __restrict__ abhh, const float* __restrict__ bbhh,
    const float* __restrict__ alpha_w, const float* __restrict__ alpha_b,
    float* __restrict__ pre, float* __restrict__ hstore)
{
    int g   = blockIdx.x / 63;
    int p   = 62 - (int)(blockIdx.x % 63);
    int tid = threadIdx.x;
    int w = tid >> 6, l = tid & 63, lg = l >> 4, lr = l & 15;
    int dimw = w * 32;
    const _Float16* gp  = g ? gpb : gpa;
    const _Float16* wf  = g ? wfb : wfa;
    const float*    bhh = g ? bbhh : abhh;

    __shared__ _Float16 hsp[2 * 32 * 256];   // 32 KB: [buf][32 rows][256], XOR-swizzled cols
    __shared__ float red[2][32][9];

    float bhn[2][4], awv[2][4];
    #pragma unroll
    for (int dt = 0; dt < 2; ++dt)
        #pragma unroll
        for (int j = 0; j < 4; ++j) {
            int d = dimw + dt * 16 + lg * 4 + j;
            bhn[dt][j] = bhh[512 + d];
            awv[dt][j] = alpha_w[d];
        }
    float ab = alpha_b[0];

    float hreg[2][2][4];
    #pragma unroll
    for (int dt = 0; dt < 2; ++dt)
        #pragma unroll
        for (int rt = 0; rt < 2; ++rt)
            #pragma unroll
            for (int j = 0; j < 4; ++j) hreg[dt][rt][j] = 0.f;

    // per-f W base pointers (in halves): frag (f,kc) lives at wfp[f] + kc*512
    const _Float16* wfp[6];
    #pragma unroll
    for (int f = 0; f < 6; ++f) {
        int ot = (f >> 1) * 16 + 2 * w + (f & 1);
        wfp[f] = wf + (size_t)ot * 4096 + (size_t)l * 8;
    }
    // prime the ring with kc = 0..3
    half8 afr[4][6];
    #pragma unroll
    for (int s = 0; s < 4; ++s)
        #pragma unroll
        for (int f = 0; f < 6; ++f)
            afr[s][f] = *reinterpret_cast<const half8*>(wfp[f] + s * 512);

    size_t tri = (size_t)p * (p + 1) / 2;

#define READBH(c, s) do { _Pragma("unroll") \
    for (int rt_ = 0; rt_ < 2; ++rt_) { \
        int r_ = rt_ * 16 + lr; \
        int cb_ = ((c) * 32 + lg * 8) ^ ((lr & 7) << 3); \
        bhv[s][rt_] = *reinterpret_cast<const half8*>(&hsp[(rb * 32 + r_) * 256 + cb_]); } } while (0)

    for (int k = 0; k <= p; ++k) {
        int t_in = p - k;
        int wr = k & 1;           // LDS write buffer this step; read buffer rb = wr^1
        int rb = wr ^ 1;
        // ---- opaque-ify W pointers: blocks cross-step CSE/hoisting of the ring loads
        #pragma unroll
        for (int f = 0; f < 6; ++f) {
            unsigned long long a_ = (unsigned long long)wfp[f];
            asm volatile("" : "+v"(a_));
            wfp[f] = (const _Float16*)a_;
        }
        // ---- drain step k-1's pre (g=0): red written before last barrier
        if (k > 0 && g == 0 && tid < 32) {
            float s = 0.f;
            #pragma unroll
            for (int q = 0; q < 8; ++q) s += red[rb][tid][q];
            pre[((size_t)p * T_ + (t_in + 1)) * B_ + tid] = 0.5f * s + ab;
        }
        // ---- issue gi loads (fp16, packed; consumed at nonlinearity)
        half8 gch[6];
        {
            const _Float16* gq = gp + ((size_t)(t_in * 8 + w) * 6) * 512 + l * 8;
            #pragma unroll
            for (int c = 0; c < 6; ++c)
                gch[c] = *reinterpret_cast<const half8*>(gq + (size_t)c * 512);
        }
        // ---- MFMA phase: acc = W @ h  (skip at k=0: h=0; ring state untouched)
        f32x4 acc[3][2][2];
        #pragma unroll
        for (int g3 = 0; g3 < 3; ++g3)
            #pragma unroll
            for (int dt = 0; dt < 2; ++dt)
                #pragma unroll
                for (int rt = 0; rt < 2; ++rt)
                    #pragma unroll
                    for (int j = 0; j < 4; ++j) acc[g3][dt][rt][j] = 0.f;
        if (k > 0) {
            half8 bhv[2][2];    // depth-2 LDS B-frag ring
            READBH(0, 0);
            READBH(1, 1);
            #pragma unroll
            for (int kc = 0; kc < 8; ++kc) {
                // consume afr[kc&3] and bhv[kc&1]
                #pragma unroll
                for (int f = 0; f < 6; ++f)
                    #pragma unroll
                    for (int rt = 0; rt < 2; ++rt)
                        acc[f >> 1][f & 1][rt] =
                            __builtin_amdgcn_mfma_f32_16x16x32_f16(afr[kc & 3][f], bhv[kc & 1][rt],
                                                                   acc[f >> 1][f & 1][rt], 0, 0, 0);
                // refill B-frag slot (kc+2)
                if (kc < 6) READBH(kc + 2, kc & 1);
                // reissue W ring slot with frag (kc+4)&7 — covers across the step boundary
                #pragma unroll
                for (int f = 0; f < 6; ++f)
                    afr[kc & 3][f] = *reinterpret_cast<const half8*>(wfp[f] + (((kc + 4) & 7) * 512));
            }
        }
        // ---- nonlinearity + state update + fp16 LDS write + direct global outputs
        #pragma unroll
        for (int dt = 0; dt < 2; ++dt)
            #pragma unroll
            for (int rt = 0; rt < 2; ++rt) {
                half4 hh;
                #pragma unroll
                for (int j = 0; j < 4; ++j) {
                    float rg = sigmoidf_(acc[0][dt][rt][j] + (float)gch[dt][rt * 4 + j]);
                    float zg = sigmoidf_(acc[1][dt][rt][j] + (float)gch[2 + dt][rt * 4 + j]);
                    float ng = tanhfast_((float)gch[4 + dt][rt * 4 + j] + rg * (acc[2][dt][rt][j] + bhn[dt][j]));
                    float h  = (1.f - zg) * ng + zg * hreg[dt][rt][j];
                    hreg[dt][rt][j] = h;
                    hh[j] = (_Float16)h;
                }
                int r  = rt * 16 + lr;
                int ce = (dimw + dt * 16 + lg * 4) ^ ((lr & 7) << 3);
                *reinterpret_cast<half4*>(&hsp[(wr * 32 + r) * 256 + ce]) = hh;
            }
        if (g) {
            // stream h (fp32) straight from registers to hstore (fire and forget)
            #pragma unroll
            for (int rt = 0; rt < 2; ++rt) {
                float* dst = hstore + ((tri + (size_t)k) * B_ + (rt * 16 + lr)) * (size_t)E_ + dimw + lg * 4;
                #pragma unroll
                for (int dt = 0; dt < 2; ++dt) {
                    f32x4 v;
                    #pragma unroll
                    for (int j = 0; j < 4; ++j) v[j] = hreg[dt][rt][j];
                    *reinterpret_cast<f32x4*>(dst + dt * 16) = v;
                }
            }
        } else {
            #pragma unroll
            for (int rt = 0; rt < 2; ++rt) {
                float pa = 0.f;
                #pragma unroll
                for (int dt = 0; dt < 2; ++dt)
                    #pragma unroll
                    for (int j = 0; j < 4; ++j) pa += hreg[dt][rt][j] * awv[dt][j];
                pa += __shfl_xor(pa, 16, 64);
                pa += __shfl_xor(pa, 32, 64);
                if (l < 16) red[wr][rt * 16 + lr][w] = pa;
            }
        }
        barrier_lds_();
    }
    // ---- epilogue: drain step p's pre
    if (g == 0 && tid < 32) {
        float s = 0.f;
        #pragma unroll
        for (int q = 0; q < 8; ++q) s += red[p & 1][tid][q];
        pre[((size_t)p * T_ + 0) * B_ + tid] = 0.5f * s + ab;
    }
#undef READBH
}

// ---------------------------------------------------------------- K4: softmax over k<=p per (p,b)
__global__ __launch_bounds__(64) void k_softmax(const float* __restrict__ pre, float* __restrict__ alpha) {
    int p = blockIdx.x >> 5, b = blockIdx.x & 31;
    int k = threadIdx.x;
    float v = (k <= p) ? pre[((size_t)p * T_ + k) * B_ + b] : -3.4e38f;
    float m = v;
    #pragma unroll
    for (int off = 32; off > 0; off >>= 1) m = fmaxf(m, __shfl_xor(m, off, 64));
    float e = (k <= p) ? __expf(v - m) : 0.f;
    float s = e;
    #pragma unroll
    for (int off = 32; off > 0; off >>= 1) s += __shfl_xor(s, off, 64);
    if (k <= p) alpha[((size_t)p * T_ + k) * B_ + b] = e / s;
}

// ---------------------------------------------------------------- K5a: U = alpha * tanh(0.5*H @ beta_w^T + beta_b), in-place;
// also context c and pred. block=(p,b), thread=e, k in register chunks of 16.
__global__ __launch_bounds__(256) void k_beta(float* __restrict__ hstore,
                                              const float* __restrict__ beta_w, const float* __restrict__ beta_b,
                                              const float* __restrict__ alpha,
                                              const float* __restrict__ emb,
                                              const float* __restrict__ out_w, const float* __restrict__ out_b,
                                              float* __restrict__ outp) {
    int p = 62 - (blockIdx.x >> 5);
    int b = blockIdx.x & 31;
    int tid = threadIdx.x;
    __shared__ float Hs[64][E_];
    size_t tri = (size_t)p * (p + 1) / 2;
    for (int k = 0; k <= p; ++k)
        Hs[k][tid] = 0.5f * hstore[((tri + (size_t)(p - k)) * B_ + b) * (size_t)E_ + tid];
    __syncthreads();
    const float* wr = beta_w + (size_t)tid * E_;
    float bb = beta_b[tid];
    float cacc = 0.f;
    int nch = (p >> 4) + 1;
    for (int kc = 0; kc < nch; ++kc) {
        float acc[16];
        #pragma unroll
        for (int kk = 0; kk < 16; ++kk) acc[kk] = 0.f;
        for (int c = 0; c < 256; c += 4) {
            float4 wv = *reinterpret_cast<const float4*>(wr + c);
            #pragma unroll
            for (int kk = 0; kk < 16; ++kk) {
                float4 hv = *reinterpret_cast<const float4*>(&Hs[kc * 16 + kk][c]);
                acc[kk] += wv.x * hv.x + wv.y * hv.y + wv.z * hv.z + wv.w * hv.w;
            }
        }
        #pragma unroll
        for (int kk = 0; kk < 16; ++kk) {
            int k = kc * 16 + kk;
            if (k <= p) {
                float beta = tanhf(acc[kk] + bb);
                float av = alpha[((size_t)p * T_ + k) * B_ + b];
                float u = av * beta;
                hstore[((tri + (size_t)k) * B_ + b) * (size_t)E_ + tid] = u;
                cacc += u * emb[((size_t)k * B_ + b) * E_ + tid];
            }
        }
    }
    float pv = cacc * out_w[tid];
    #pragma unroll
    for (int off = 32; off > 0; off >>= 1) pv += __shfl_down(pv, off, 64);
    __shared__ float prr[4];
    if ((tid & 63) == 0) prr[tid >> 6] = pv;
    __syncthreads();
    if (tid == 0) outp[(size_t)b * P_ + p] = prr[0] + prr[1] + prr[2] + prr[3] + out_b[0];
}

// ---------------------------------------------------------------- K5c: weight[b,p,i] = (1/(p+1)) * sum_k (U[k]@M)[i] * x[b,k,i]
__global__ __launch_bounds__(256) void k_wout(const float* __restrict__ ustore,
                                              const float* __restrict__ Mmat,
                                              const float* __restrict__ x,
                                              float* __restrict__ out) {
    int p = 62 - (blockIdx.x >> 5);
    int b = blockIdx.x & 31;
    int tid = threadIdx.x;
    __shared__ float Ut[E_][68];
    size_t tri = (size_t)p * (p + 1) / 2;
    for (int k = 0; k <= p; ++k)
        Ut[tid][k] = ustore[((tri + (size_t)k) * B_ + b) * (size_t)E_ + tid];
    __syncthreads();
    float gacc = 0.f;
    int nch = (p >> 4) + 1;
    const float* xb = x + (size_t)b * T_ * 256;
    for (int kc = 0; kc < nch; ++kc) {
        float acc[16];
        #pragma unroll
        for (int kk = 0; kk < 16; ++kk) acc[kk] = 0.f;
        for (int e = 0; e < 256; ++e) {
            float m = Mmat[(size_t)e * 256 + tid];
            const float4* up = reinterpret_cast<const float4*>(&Ut[e][kc * 16]);
            float4 u0 = up[0], u1 = up[1], u2 = up[2], u3 = up[3];
            acc[0]  += u0.x * m; acc[1]  += u0.y * m; acc[2]  += u0.z * m; acc[3]  += u0.w * m;
            acc[4]  += u1.x * m; acc[5]  += u1.y * m; acc[6]  += u1.z * m; acc[7]  += u1.w * m;
            acc[8]  += u2.x * m; acc[9]  += u2.y * m; acc[10] += u2.z * m; acc[11] += u2.w * m;
            acc[12] += u3.x * m; acc[13] += u3.y * m; acc[14] += u3.z * m; acc[15] += u3.w * m;
        }
        #pragma unroll
        for (int kk = 0; kk < 16; ++kk) {
            int k = kc * 16 + kk;
            if (k <= p) gacc += acc[kk] * xb[(size_t)k * 256 + tid];
        }
    }
    out[2016 + ((size_t)b * P_ + p) * 256 + tid] = gacc / (float)(p + 1);
}

// ---------------------------------------------------------------- host
extern "C" void kernel_launch(void* const* d_in, const int* in_sizes, int n_in,
                              void* d_out, int out_size, void* d_ws, size_t ws_size,
                              hipStream_t stream) {
    const float* x       = (const float*)d_in[0];
    const float* emb_w   = (const float*)d_in[1];
    const float* emb_b   = (const float*)d_in[2];
    const float* a_wih   = (const float*)d_in[3];
    const float* a_whh   = (const float*)d_in[4];
    const float* a_bih   = (const float*)d_in[5];
    const float* a_bhh   = (const float*)d_in[6];
    const float* b_wih   = (const float*)d_in[7];
    const float* b_whh   = (const float*)d_in[8];
    const float* b_bih   = (const float*)d_in[9];
    const float* b_bhh   = (const float*)d_in[10];
    const float* alpha_w = (const float*)d_in[11];
    const float* alpha_b = (const float*)d_in[12];
    const float* beta_w  = (const float*)d_in[13];
    const float* beta_b  = (const float*)d_in[14];
    const float* out_w   = (const float*)d_in[15];
    const float* out_b   = (const float*)d_in[16];
    float* out = (float*)d_out;

    float* ws = (float*)d_ws;
    // ws layout (floats), total 20,705,280 floats = 82.8 MB
    float* emb      = ws;                            // 524288
    _Float16* giTa  = (_Float16*)(emb + 524288);     // 768*2048 h = 786432 f
    _Float16* giTb  = giTa + 1572864;                // 786432 f
    _Float16* gpa   = giTb + 1572864;                // 786432 f
    _Float16* gpb   = gpa  + 1572864;                // 786432 f
    float* Mmat     = (float*)(gpb + 1572864);       // 65536
    float* pre      = Mmat  + 65536;                 // 129024
    float* alpha    = pre   + 129024;                // 129024
    _Float16* wfa   = (_Float16*)(alpha + 129024);   // 196608 h = 98304 f
    _Float16* wfb   = wfa + 196608;                  // 98304 f
    float* hstore   = (float*)(wfb + 196608);        // 16515072

    k_prep<<<256, 256, 0, stream>>>(emb_w, out_w, Mmat);
    k_emb<<<2048, 256, 0, stream>>>(x, emb_w, emb_b, emb);
    k_gates<<<256, 256, 0, stream>>>(emb, a_wih, a_bih, a_bhh, b_wih, b_bih, b_bhh, giTa, giTb);
    k_wfrag<<<384, 64, 0, stream>>>(a_whh, wfa);
    k_wfrag<<<384, 64, 0, stream>>>(b_whh, wfb);
    k_gipack<<<128, 512, 0, stream>>>(giTa, giTb, gpa, gpb);
    k_gru_f<<<126, 512, 0, stream>>>(gpa, gpb, wfa, wfb, a_bhh, b_bhh,
                                     alpha_w, alpha_b, pre, hstore);
    k_softmax<<<2016, 64, 0, stream>>>(pre, alpha);
    k_beta<<<2016, 256, 0, stream>>>(hstore, beta_w, beta_b, alpha, emb, out_w, out_b, out);
    k_wout<<<2016, 256, 0, stream>>>(hstore, Mmat, x, out);
}

// Round 6
// 907.821 us; speedup vs baseline: 1.2585x; 1.2585x over previous
//
#include <hip/hip_runtime.h>
#include <math.h>

// Problem constants: B=32, T=64, I=E=Ha=Hb=256, O=1, P=T-1=63
#define B_   32
#define T_   64
#define P_   63
#define E_   256
#define G3_  768

typedef _Float16 half8 __attribute__((ext_vector_type(8)));
typedef _Float16 half4 __attribute__((ext_vector_type(4)));
typedef float    f32x4 __attribute__((ext_vector_type(4)));

__device__ __forceinline__ float sigmoidf_(float x) { return 1.0f / (1.0f + __expf(-x)); }
__device__ __forceinline__ float tanhfast_(float x) { float e = __expf(2.0f*x); return 1.0f - 2.0f/(e + 1.0f); }

// Barrier WITHOUT vmcnt drain: only LDS ops must be visible across it.
__device__ __forceinline__ void barrier_lds_() {
    asm volatile("" ::: "memory");
    asm volatile("s_waitcnt lgkmcnt(0)" ::: "memory");
    __builtin_amdgcn_s_barrier();
    asm volatile("" ::: "memory");
}

// ---------------------------------------------------------------- K0: M[e,i] = out_w0[e]*emb_w[e,i]
__global__ __launch_bounds__(256) void k_prep(const float* __restrict__ emb_w,
                                              const float* __restrict__ out_w,
                                              float* __restrict__ Mmat) {
    int e = blockIdx.x, i = threadIdx.x;
    Mmat[(size_t)e * 256 + i] = out_w[e] * emb_w[(size_t)e * 256 + i];
}

// ---------------------------------------------------------------- K1: emb[t,b,e] = emb_w @ x[b,t,:] + emb_b
__global__ __launch_bounds__(256) void k_emb(const float* __restrict__ x,
                                             const float* __restrict__ emb_w,
                                             const float* __restrict__ emb_b,
                                             float* __restrict__ emb) {
    int t = blockIdx.x >> 5, b = blockIdx.x & 31;
    int tid = threadIdx.x;
    __shared__ float xr[E_];
    xr[tid] = x[((size_t)b * T_ + t) * E_ + tid];
    __syncthreads();
    const float* wr = emb_w + (size_t)tid * E_;
    float acc = emb_b[tid];
    for (int c = 0; c < 256; c += 4) {
        float4 wv = *reinterpret_cast<const float4*>(wr + c);
        float4 xv = *reinterpret_cast<const float4*>(&xr[c]);
        acc += wv.x * xv.x + wv.y * xv.y + wv.z * xv.z + wv.w * xv.w;
    }
    emb[((size_t)t * B_ + b) * E_ + tid] = acc;
}

// ---------------------------------------------------------------- K2: input gates -> fp16, transposed [o][r]
// b_ih folded always; b_hh folded for r,z gates only (n-gate's b_hh enters inside r*).
__global__ __launch_bounds__(256) void k_gates(const float* __restrict__ emb,
                                               const float* __restrict__ awih, const float* __restrict__ abih,
                                               const float* __restrict__ abhh,
                                               const float* __restrict__ bwih, const float* __restrict__ bbih,
                                               const float* __restrict__ bbhh,
                                               _Float16* __restrict__ giTa, _Float16* __restrict__ giTb) {
    int r0 = blockIdx.x * 8;
    int tid = threadIdx.x;
    __shared__ float es[8][E_];
    for (int rr = 0; rr < 8; ++rr) es[rr][tid] = emb[(size_t)(r0 + rr) * E_ + tid];
    __syncthreads();
    for (int gs = 0; gs < 6; ++gs) {
        const float* W    = (gs < 3) ? awih : bwih;
        const float* bih  = (gs < 3) ? abih : bbih;
        const float* bhh  = (gs < 3) ? abhh : bbhh;
        _Float16* giT     = (gs < 3) ? giTa : giTb;
        int gate = gs % 3;
        int grow = gate * 256 + tid;
        const float* wr = W + (size_t)grow * E_;
        float acc[8];
        #pragma unroll
        for (int rr = 0; rr < 8; ++rr) acc[rr] = 0.f;
        for (int c = 0; c < 256; c += 4) {
            float4 wv = *reinterpret_cast<const float4*>(wr + c);
            #pragma unroll
            for (int rr = 0; rr < 8; ++rr) {
                float4 ev = *reinterpret_cast<const float4*>(&es[rr][c]);
                acc[rr] += wv.x * ev.x + wv.y * ev.y + wv.z * ev.z + wv.w * ev.w;
            }
        }
        float bv = bih[grow] + ((gate < 2) ? bhh[grow] : 0.f);
        _Float16* dst = giT + (size_t)grow * 2048 + r0;
        #pragma unroll
        for (int rr = 0; rr < 8; ++rr) dst[rr] = (_Float16)(acc[rr] + bv);
    }
}

// ---------------------------------------------------------------- K2b: W_hh -> fp16 MFMA A-fragments
// wf[((ot*8+kc)*64 + lane)*8 + j] = (fp16) whh[ot*16 + (lane&15)][kc*32 + (lane>>4)*8 + j]
__global__ __launch_bounds__(64) void k_wfrag(const float* __restrict__ whh, _Float16* __restrict__ wf) {
    int ot = blockIdx.x >> 3, kc = blockIdx.x & 7, l = threadIdx.x;
    int orow = ot * 16 + (l & 15);
    int c0   = kc * 32 + (l >> 4) * 8;
    half8 v;
    #pragma unroll
    for (int j = 0; j < 8; ++j) v[j] = (_Float16)whh[(size_t)orow * 256 + c0 + j];
    *reinterpret_cast<half8*>(&wf[((size_t)(ot * 8 + kc) * 64 + l) * 8]) = v;
}

// ---------------------------------------------------------------- K2c: pack gi for the 4-wave / 16-batch k_gru_f.
// Per (g,t,bh,wave w) 6 chunks of 512 halves; thread (w,l) chunk c holds values for
// gate g3=c>>1, tiles i=(c&1)*2+(e>>2), dim = 64w+16i+lg*4+(e&3), batch = bh*16+lr.
__global__ __launch_bounds__(256) void k_gipack(const _Float16* __restrict__ gA, const _Float16* __restrict__ gB,
                                                _Float16* __restrict__ pA, _Float16* __restrict__ pB) {
    int bid = blockIdx.x;
    int g = bid >> 7, t = (bid >> 1) & 63, bh = bid & 1;
    const _Float16* src = g ? gB : gA;
    _Float16*       dst = g ? pB : pA;
    int tid = threadIdx.x, w = tid >> 6, l = tid & 63, lg = l >> 4, lr = l & 15;
    int b = bh * 16 + lr;
    #pragma unroll
    for (int c = 0; c < 6; ++c) {
        int g3 = c >> 1, ih = c & 1;
        half8 v;
        #pragma unroll
        for (int e = 0; e < 8; ++e) {
            int i = ih * 2 + (e >> 2), j = e & 3;
            int o = g3 * 256 + 64 * w + 16 * i + lg * 4 + j;
            v[e] = src[(size_t)o * 2048 + t * 32 + b];
        }
        *reinterpret_cast<half8*>(&dst[(((size_t)(t * 2 + bh) * 4 + w) * 6 + c) * 512 + l * 8]) = v;
    }
}

// ---------------------------------------------------------------- K3: triangular GRU chains, W-persistent.
// block = (g, p, bh): 252 blocks x 256 threads (4 waves, 1/SIMD, 512-VGPR budget).
// Wave w owns out-dims [64w,64w+64) of each gate; 16 batch rows (bh half).
// W_hh fragments: kc 0..5 in REGISTERS (loaded once, 288 VGPR), kc 6..7 in LDS (96 KB,
// filled once). Steady-state global traffic per step = 6 gi loads (+ h stores for g=1).
// h fp32 in regs; fp16 copy in double-buffered swizzled LDS; lgkm-only barrier per step.
__global__ __launch_bounds__(256, 1) void k_gru_f(
    const _Float16* __restrict__ gpa, const _Float16* __restrict__ gpb,
    const _Float16* __restrict__ wfa, const _Float16* __restrict__ wfb,
    const float* __restrict__ abhh, const float* __restrict__ bbhh,
    const float* __restrict__ alpha_w, const float* __restrict__ alpha_b,
    float* __restrict__ pre, float* __restrict__ hstore)
{
    extern __shared__ char smem[];
    half8*    wlds = reinterpret_cast<half8*>(smem);              // [48 ot][2 kc][64 l] = 96 KB
    _Float16* hsp  = reinterpret_cast<_Float16*>(smem + 98304);   // [2 buf][16 rows][256] = 16 KB
    float*    red  = reinterpret_cast<float*>(smem + 98304 + 16384);  // [2][16][4]

    int bid = blockIdx.x;
    int g   = bid / 126;
    int rr_ = bid % 126;
    int p   = 62 - (rr_ >> 1);
    int bh  = rr_ & 1;
    int tid = threadIdx.x;
    int w = tid >> 6, l = tid & 63, lg = l >> 4, lr = l & 15;
    const _Float16* gp  = g ? gpb : gpa;
    const _Float16* wf  = g ? wfb : wfa;
    const float*    bhh = g ? bbhh : abhh;

    // ---- prologue: W kc 0..5 into registers (once)
    half8 wreg[3][4][6];
    #pragma unroll
    for (int g3 = 0; g3 < 3; ++g3)
        #pragma unroll
        for (int i = 0; i < 4; ++i) {
            int ot = g3 * 16 + 4 * w + i;
            #pragma unroll
            for (int kc = 0; kc < 6; ++kc)
                wreg[g3][i][kc] = *reinterpret_cast<const half8*>(&wf[((size_t)(ot * 8 + kc) * 64 + l) * 8]);
        }
    // ---- prologue: W kc 6..7 into LDS (once)
    #pragma unroll
    for (int q = 0; q < 24; ++q) {
        int idx = q * 256 + tid;           // 48*2*64 = 6144 half8
        int ot = idx >> 7, kcs = (idx >> 6) & 1, l2 = idx & 63;
        wlds[idx] = *reinterpret_cast<const half8*>(&wf[((size_t)(ot * 8 + 6 + kcs) * 64 + l2) * 8]);
    }
    float bhn[4][4], awv[4][4];
    #pragma unroll
    for (int i = 0; i < 4; ++i)
        #pragma unroll
        for (int j = 0; j < 4; ++j) {
            int d = 64 * w + 16 * i + lg * 4 + j;
            bhn[i][j] = bhh[512 + d];
            awv[i][j] = alpha_w[d];
        }
    float ab = alpha_b[0];
    float hreg[4][4];
    #pragma unroll
    for (int i = 0; i < 4; ++i)
        #pragma unroll
        for (int j = 0; j < 4; ++j) hreg[i][j] = 0.f;
    __syncthreads();   // wlds visible to all waves (one-time full sync)

    size_t tri = (size_t)p * (p + 1) / 2;

    for (int k = 0; k <= p; ++k) {
        int t_in = p - k;
        int wr = k & 1, rb = wr ^ 1;
        // ---- drain step k-1's pre (g=0)
        if (k > 0 && g == 0 && tid < 16) {
            float s = red[((rb * 16 + tid) << 2) + 0] + red[((rb * 16 + tid) << 2) + 1]
                    + red[((rb * 16 + tid) << 2) + 2] + red[((rb * 16 + tid) << 2) + 3];
            pre[((size_t)p * T_ + (t_in + 1)) * B_ + bh * 16 + tid] = 0.5f * s + ab;
        }
        // ---- gi loads (consumed at nonlinearity; covered by MFMA phase)
        half8 gch[6];
        {
            const _Float16* gq = gp + (((size_t)(t_in * 2 + bh) * 4 + w) * 6) * 512 + l * 8;
            #pragma unroll
            for (int c = 0; c < 6; ++c)
                gch[c] = *reinterpret_cast<const half8*>(gq + (size_t)c * 512);
        }
        // ---- MFMA: acc = W @ h (skip at k=0)
        f32x4 acc[3][4];
        #pragma unroll
        for (int g3 = 0; g3 < 3; ++g3)
            #pragma unroll
            for (int i = 0; i < 4; ++i)
                #pragma unroll
                for (int j = 0; j < 4; ++j) acc[g3][i][j] = 0.f;
        if (k > 0) {
            half8 bhv[2];
            {
                int cb = (lg * 8) ^ ((lr & 7) << 3);
                bhv[0] = *reinterpret_cast<const half8*>(&hsp[(rb * 16 + lr) * 256 + cb]);
            }
            #pragma unroll
            for (int kc = 0; kc < 8; ++kc) {
                if (kc < 7) {
                    int cb = ((kc + 1) * 32 + lg * 8) ^ ((lr & 7) << 3);
                    bhv[(kc + 1) & 1] = *reinterpret_cast<const half8*>(&hsp[(rb * 16 + lr) * 256 + cb]);
                }
                if (kc < 6) {
                    #pragma unroll
                    for (int g3 = 0; g3 < 3; ++g3)
                        #pragma unroll
                        for (int i = 0; i < 4; ++i)
                            acc[g3][i] = __builtin_amdgcn_mfma_f32_16x16x32_f16(
                                wreg[g3][i][kc], bhv[kc & 1], acc[g3][i], 0, 0, 0);
                } else {
                    #pragma unroll
                    for (int g3 = 0; g3 < 3; ++g3)
                        #pragma unroll
                        for (int i = 0; i < 4; ++i) {
                            half8 wlv = wlds[((g3 * 16 + 4 * w + i) * 2 + (kc - 6)) * 64 + l];
                            acc[g3][i] = __builtin_amdgcn_mfma_f32_16x16x32_f16(
                                wlv, bhv[kc & 1], acc[g3][i], 0, 0, 0);
                        }
                }
            }
        }
        // ---- nonlinearity + state update + fp16 LDS write
        #pragma unroll
        for (int i = 0; i < 4; ++i) {
            half4 hh;
            #pragma unroll
            for (int j = 0; j < 4; ++j) {
                int c = i >> 1, e = (i & 1) * 4 + j;
                float rg = sigmoidf_(acc[0][i][j] + (float)gch[c][e]);
                float zg = sigmoidf_(acc[1][i][j] + (float)gch[2 + c][e]);
                float ng = tanhfast_((float)gch[4 + c][e] + rg * (acc[2][i][j] + bhn[i][j]));
                float h  = (1.f - zg) * ng + zg * hreg[i][j];
                hreg[i][j] = h;
                hh[j] = (_Float16)h;
            }
            int ce = (64 * w + 16 * i + lg * 4) ^ ((lr & 7) << 3);
            *reinterpret_cast<half4*>(&hsp[(wr * 16 + lr) * 256 + ce]) = hh;
        }
        if (g) {
            // stream h (fp32) to hstore (fire and forget)
            float* dst = hstore + ((tri + (size_t)k) * B_ + bh * 16 + lr) * (size_t)E_ + 64 * w + lg * 4;
            #pragma unroll
            for (int i = 0; i < 4; ++i) {
                f32x4 v;
                #pragma unroll
                for (int j = 0; j < 4; ++j) v[j] = hreg[i][j];
                *reinterpret_cast<f32x4*>(dst + 16 * i) = v;
            }
        } else {
            float pa = 0.f;
            #pragma unroll
            for (int i = 0; i < 4; ++i)
                #pragma unroll
                for (int j = 0; j < 4; ++j) pa += hreg[i][j] * awv[i][j];
            pa += __shfl_xor(pa, 16, 64);
            pa += __shfl_xor(pa, 32, 64);
            if (l < 16) red[((wr * 16 + l) << 2) + w] = pa;
        }
        barrier_lds_();
    }
    // ---- epilogue: drain step p's pre
    if (g == 0 && tid < 16) {
        int wl = p & 1;
        float s = red[((wl * 16 + tid) << 2) + 0] + red[((wl * 16 + tid) << 2) + 1]
                + red[((wl * 16 + tid) << 2) + 2] + red[((wl * 16 + tid) << 2) + 3];
        pre[((size_t)p * T_ + 0) * B_ + bh * 16 + tid] = 0.5f * s + ab;
    }
}

// ---------------------------------------------------------------- K4: softmax over k<=p per (p,b)
__global__ __launch_bounds__(64) void k_softmax(const float* __restrict__ pre, float* __restrict__ alpha) {
    int p = blockIdx.x >> 5, b = blockIdx.x & 31;
    int k = threadIdx.x;
    float v = (k <= p) ? pre[((size_t)p * T_ + k) * B_ + b] : -3.4e38f;
    float m = v;
    #pragma unroll
    for (int off = 32; off > 0; off >>= 1) m = fmaxf(m, __shfl_xor(m, off, 64));
    float e = (k <= p) ? __expf(v - m) : 0.f;
    float s = e;
    #pragma unroll
    for (int off = 32; off > 0; off >>= 1) s += __shfl_xor(s, off, 64);
    if (k <= p) alpha[((size_t)p * T_ + k) * B_ + b] = e / s;
}

// ---------------------------------------------------------------- K5a: U = alpha * tanh(0.5*H @ beta_w^T + beta_b), in-place;
// also context c and pred. block=(p,b), thread=e, k in register chunks of 16.
__global__ __launch_bounds__(256) void k_beta(float* __restrict__ hstore,
                                              const float* __restrict__ beta_w, const float* __restrict__ beta_b,
                                              const float* __restrict__ alpha,
                                              const float* __restrict__ emb,
                                              const float* __restrict__ out_w, const float* __restrict__ out_b,
                                              float* __restrict__ outp) {
    int p = 62 - (blockIdx.x >> 5);
    int b = blockIdx.x & 31;
    int tid = threadIdx.x;
    __shared__ float Hs[64][E_];
    size_t tri = (size_t)p * (p + 1) / 2;
    for (int k = 0; k <= p; ++k)
        Hs[k][tid] = 0.5f * hstore[((tri + (size_t)(p - k)) * B_ + b) * (size_t)E_ + tid];
    __syncthreads();
    const float* wr = beta_w + (size_t)tid * E_;
    float bb = beta_b[tid];
    float cacc = 0.f;
    int nch = (p >> 4) + 1;
    for (int kc = 0; kc < nch; ++kc) {
        float acc[16];
        #pragma unroll
        for (int kk = 0; kk < 16; ++kk) acc[kk] = 0.f;
        for (int c = 0; c < 256; c += 4) {
            float4 wv = *reinterpret_cast<const float4*>(wr + c);
            #pragma unroll
            for (int kk = 0; kk < 16; ++kk) {
                float4 hv = *reinterpret_cast<const float4*>(&Hs[kc * 16 + kk][c]);
                acc[kk] += wv.x * hv.x + wv.y * hv.y + wv.z * hv.z + wv.w * hv.w;
            }
        }
        #pragma unroll
        for (int kk = 0; kk < 16; ++kk) {
            int k = kc * 16 + kk;
            if (k <= p) {
                float beta = tanhf(acc[kk] + bb);
                float av = alpha[((size_t)p * T_ + k) * B_ + b];
                float u = av * beta;
                hstore[((tri + (size_t)k) * B_ + b) * (size_t)E_ + tid] = u;
                cacc += u * emb[((size_t)k * B_ + b) * E_ + tid];
            }
        }
    }
    float pv = cacc * out_w[tid];
    #pragma unroll
    for (int off = 32; off > 0; off >>= 1) pv += __shfl_down(pv, off, 64);
    __shared__ float prr[4];
    if ((tid & 63) == 0) prr[tid >> 6] = pv;
    __syncthreads();
    if (tid == 0) outp[(size_t)b * P_ + p] = prr[0] + prr[1] + prr[2] + prr[3] + out_b[0];
}

// ---------------------------------------------------------------- K5c: weight[b,p,i] = (1/(p+1)) * sum_k (U[k]@M)[i] * x[b,k,i]
__global__ __launch_bounds__(256) void k_wout(const float* __restrict__ ustore,
                                              const float* __restrict__ Mmat,
                                              const float* __restrict__ x,
                                              float* __restrict__ out) {
    int p = 62 - (blockIdx.x >> 5);
    int b = blockIdx.x & 31;
    int tid = threadIdx.x;
    __shared__ float Ut[E_][68];
    size_t tri = (size_t)p * (p + 1) / 2;
    for (int k = 0; k <= p; ++k)
        Ut[tid][k] = ustore[((tri + (size_t)k) * B_ + b) * (size_t)E_ + tid];
    __syncthreads();
    float gacc = 0.f;
    int nch = (p >> 4) + 1;
    const float* xb = x + (size_t)b * T_ * 256;
    for (int kc = 0; kc < nch; ++kc) {
        float acc[16];
        #pragma unroll
        for (int kk = 0; kk < 16; ++kk) acc[kk] = 0.f;
        for (int e = 0; e < 256; ++e) {
            float m = Mmat[(size_t)e * 256 + tid];
            const float4* up = reinterpret_cast<const float4*>(&Ut[e][kc * 16]);
            float4 u0 = up[0], u1 = up[1], u2 = up[2], u3 = up[3];
            acc[0]  += u0.x * m; acc[1]  += u0.y * m; acc[2]  += u0.z * m; acc[3]  += u0.w * m;
            acc[4]  += u1.x * m; acc[5]  += u1.y * m; acc[6]  += u1.z * m; acc[7]  += u1.w * m;
            acc[8]  += u2.x * m; acc[9]  += u2.y * m; acc[10] += u2.z * m; acc[11] += u2.w * m;
            acc[12] += u3.x * m; acc[13] += u3.y * m; acc[14] += u3.z * m; acc[15] += u3.w * m;
        }
        #pragma unroll
        for (int kk = 0; kk < 16; ++kk) {
            int k = kc * 16 + kk;
            if (k <= p) gacc += acc[kk] * xb[(size_t)k * 256 + tid];
        }
    }
    out[2016 + ((size_t)b * P_ + p) * 256 + tid] = gacc / (float)(p + 1);
}

// ---------------------------------------------------------------- host
extern "C" void kernel_launch(void* const* d_in, const int* in_sizes, int n_in,
                              void* d_out, int out_size, void* d_ws, size_t ws_size,
                              hipStream_t stream) {
    const float* x       = (const float*)d_in[0];
    const float* emb_w   = (const float*)d_in[1];
    const float* emb_b   = (const float*)d_in[2];
    const float* a_wih   = (const float*)d_in[3];
    const float* a_whh   = (const float*)d_in[4];
    const float* a_bih   = (const float*)d_in[5];
    const float* a_bhh   = (const float*)d_in[6];
    const float* b_wih   = (const float*)d_in[7];
    const float* b_whh   = (const float*)d_in[8];
    const float* b_bih   = (const float*)d_in[9];
    const float* b_bhh   = (const float*)d_in[10];
    const float* alpha_w = (const float*)d_in[11];
    const float* alpha_b = (const float*)d_in[12];
    const float* beta_w  = (const float*)d_in[13];
    const float* beta_b  = (const float*)d_in[14];
    const float* out_w   = (const float*)d_in[15];
    const float* out_b   = (const float*)d_in[16];
    float* out = (float*)d_out;

    float* ws = (float*)d_ws;
    // ws layout (floats), total 20,705,280 floats = 82.8 MB
    float* emb      = ws;                            // 524288
    _Float16* giTa  = (_Float16*)(emb + 524288);     // 768*2048 h = 786432 f
    _Float16* giTb  = giTa + 1572864;                // 786432 f
    _Float16* gpa   = giTb + 1572864;                // 786432 f
    _Float16* gpb   = gpa  + 1572864;                // 786432 f
    float* Mmat     = (float*)(gpb + 1572864);       // 65536
    float* pre      = Mmat  + 65536;                 // 129024
    float* alpha    = pre   + 129024;                // 129024
    _Float16* wfa   = (_Float16*)(alpha + 129024);   // 196608 h = 98304 f
    _Float16* wfb   = wfa + 196608;                  // 98304 f
    float* hstore   = (float*)(wfb + 196608);        // 16515072

    const int GRU_LDS = 98304 + 16384 + 512;         // 115200 B dynamic LDS
    (void)hipFuncSetAttribute((const void*)k_gru_f,
                              hipFuncAttributeMaxDynamicSharedMemorySize, GRU_LDS);

    k_prep<<<256, 256, 0, stream>>>(emb_w, out_w, Mmat);
    k_emb<<<2048, 256, 0, stream>>>(x, emb_w, emb_b, emb);
    k_gates<<<256, 256, 0, stream>>>(emb, a_wih, a_bih, a_bhh, b_wih, b_bih, b_bhh, giTa, giTb);
    k_wfrag<<<384, 64, 0, stream>>>(a_whh, wfa);
    k_wfrag<<<384, 64, 0, stream>>>(b_whh, wfb);
    k_gipack<<<256, 256, 0, stream>>>(giTa, giTb, gpa, gpb);
    k_gru_f<<<252, 256, GRU_LDS, stream>>>(gpa, gpb, wfa, wfb, a_bhh, b_bhh,
                                           alpha_w, alpha_b, pre, hstore);
    k_softmax<<<2016, 64, 0, stream>>>(pre, alpha);
    k_beta<<<2016, 256, 0, stream>>>(hstore, beta_w, beta_b, alpha, emb, out_w, out_b, out);
    k_wout<<<2016, 256, 0, stream>>>(hstore, Mmat, x, out);
}

// Round 7
// 505.923 us; speedup vs baseline: 2.2583x; 1.7944x over previous
//
#include <hip/hip_runtime.h>
#include <math.h>

// Problem constants: B=32, T=64, I=E=Ha=Hb=256, O=1, P=T-1=63
#define B_   32
#define T_   64
#define P_   63
#define E_   256
#define G3_  768

typedef _Float16 half8 __attribute__((ext_vector_type(8)));
typedef _Float16 half4 __attribute__((ext_vector_type(4)));
typedef float    f32x4 __attribute__((ext_vector_type(4)));

__device__ __forceinline__ float sigmoidf_(float x) { return 1.0f / (1.0f + __expf(-x)); }
__device__ __forceinline__ float tanhfast_(float x) { float e = __expf(2.0f*x); return 1.0f - 2.0f/(e + 1.0f); }

// Barrier WITHOUT vmcnt drain: only LDS ops must be visible across it.
__device__ __forceinline__ void barrier_lds_() {
    asm volatile("" ::: "memory");
    asm volatile("s_waitcnt lgkmcnt(0)" ::: "memory");
    __builtin_amdgcn_s_barrier();
    asm volatile("" ::: "memory");
}

// ---------------------------------------------------------------- K1: emb[t,b,e] = emb_w @ x[b,t,:] + emb_b ; ewh = fp16(emb*out_w)
__global__ __launch_bounds__(256) void k_emb(const float* __restrict__ x,
                                             const float* __restrict__ emb_w,
                                             const float* __restrict__ emb_b,
                                             const float* __restrict__ out_w,
                                             float* __restrict__ emb,
                                             _Float16* __restrict__ ewh) {
    int t = blockIdx.x >> 5, b = blockIdx.x & 31;
    int tid = threadIdx.x;
    __shared__ float xr[E_];
    xr[tid] = x[((size_t)b * T_ + t) * E_ + tid];
    __syncthreads();
    const float* wr = emb_w + (size_t)tid * E_;
    float acc = emb_b[tid];
    for (int c = 0; c < 256; c += 4) {
        float4 wv = *reinterpret_cast<const float4*>(wr + c);
        float4 xv = *reinterpret_cast<const float4*>(&xr[c]);
        acc += wv.x * xv.x + wv.y * xv.y + wv.z * xv.z + wv.w * xv.w;
    }
    size_t o = ((size_t)t * B_ + b) * E_ + tid;
    emb[o] = acc;
    ewh[o] = (_Float16)(acc * out_w[tid]);
}

// ---------------------------------------------------------------- K2: input gates -> fp16, transposed [o][r]
__global__ __launch_bounds__(256) void k_gates(const float* __restrict__ emb,
                                               const float* __restrict__ awih, const float* __restrict__ abih,
                                               const float* __restrict__ abhh,
                                               const float* __restrict__ bwih, const float* __restrict__ bbih,
                                               const float* __restrict__ bbhh,
                                               _Float16* __restrict__ giTa, _Float16* __restrict__ giTb) {
    int r0 = blockIdx.x * 8;
    int tid = threadIdx.x;
    __shared__ float es[8][E_];
    for (int rr = 0; rr < 8; ++rr) es[rr][tid] = emb[(size_t)(r0 + rr) * E_ + tid];
    __syncthreads();
    for (int gs = 0; gs < 6; ++gs) {
        const float* W    = (gs < 3) ? awih : bwih;
        const float* bih  = (gs < 3) ? abih : bbih;
        const float* bhh  = (gs < 3) ? abhh : bbhh;
        _Float16* giT     = (gs < 3) ? giTa : giTb;
        int gate = gs % 3;
        int grow = gate * 256 + tid;
        const float* wr = W + (size_t)grow * E_;
        float acc[8];
        #pragma unroll
        for (int rr = 0; rr < 8; ++rr) acc[rr] = 0.f;
        for (int c = 0; c < 256; c += 4) {
            float4 wv = *reinterpret_cast<const float4*>(wr + c);
            #pragma unroll
            for (int rr = 0; rr < 8; ++rr) {
                float4 ev = *reinterpret_cast<const float4*>(&es[rr][c]);
                acc[rr] += wv.x * ev.x + wv.y * ev.y + wv.z * ev.z + wv.w * ev.w;
            }
        }
        float bv = bih[grow] + ((gate < 2) ? bhh[grow] : 0.f);
        _Float16* dst = giT + (size_t)grow * 2048 + r0;
        #pragma unroll
        for (int rr = 0; rr < 8; ++rr) dst[rr] = (_Float16)(acc[rr] + bv);
    }
}

// ---------------------------------------------------------------- K2b: row-major fp32 W -> fp16 MFMA A-fragments (with scale)
// wf[((ot*8+kc)*64 + lane)*8 + j] = (fp16)(scale * W[ot*16 + (lane&15)][kc*32 + (lane>>4)*8 + j])
__global__ __launch_bounds__(64) void k_wfrag(const float* __restrict__ whh, _Float16* __restrict__ wf, float scale) {
    int ot = blockIdx.x >> 3, kc = blockIdx.x & 7, l = threadIdx.x;
    int orow = ot * 16 + (l & 15);
    int c0   = kc * 32 + (l >> 4) * 8;
    half8 v;
    #pragma unroll
    for (int j = 0; j < 8; ++j) v[j] = (_Float16)(scale * whh[(size_t)orow * 256 + c0 + j]);
    *reinterpret_cast<half8*>(&wf[((size_t)(ot * 8 + kc) * 64 + l) * 8]) = v;
}

// ---------------------------------------------------------------- K2m: M^T A-frags: A[row=i][k=e] = out_w[e]*emb_w[e][i]
__global__ __launch_bounds__(64) void k_mfrag(const float* __restrict__ emb_w, const float* __restrict__ out_w,
                                              _Float16* __restrict__ mf) {
    int ot = blockIdx.x >> 3, kc = blockIdx.x & 7, l = threadIdx.x;
    int i  = ot * 16 + (l & 15);
    int e0 = kc * 32 + (l >> 4) * 8;
    half8 v;
    #pragma unroll
    for (int j = 0; j < 8; ++j) v[j] = (_Float16)(out_w[e0 + j] * emb_w[(size_t)(e0 + j) * 256 + i]);
    *reinterpret_cast<half8*>(&mf[((size_t)(ot * 8 + kc) * 64 + l) * 8]) = v;
}

// ---------------------------------------------------------------- K2x: x -> fp16 copy (same flat layout)
__global__ __launch_bounds__(256) void k_xh(const float* __restrict__ x, _Float16* __restrict__ xh) {
    int i = blockIdx.x * 256 + threadIdx.x;
    xh[i] = (_Float16)x[i];
}

// ---------------------------------------------------------------- K2c: pack gi for the 4-wave / 16-batch k_gru_f.
__global__ __launch_bounds__(256) void k_gipack(const _Float16* __restrict__ gA, const _Float16* __restrict__ gB,
                                                _Float16* __restrict__ pA, _Float16* __restrict__ pB) {
    int bid = blockIdx.x;
    int g = bid >> 7, t = (bid >> 1) & 63, bh = bid & 1;
    const _Float16* src = g ? gB : gA;
    _Float16*       dst = g ? pB : pA;
    int tid = threadIdx.x, w = tid >> 6, l = tid & 63, lg = l >> 4, lr = l & 15;
    int b = bh * 16 + lr;
    #pragma unroll
    for (int c = 0; c < 6; ++c) {
        int g3 = c >> 1, ih = c & 1;
        half8 v;
        #pragma unroll
        for (int e = 0; e < 8; ++e) {
            int i = ih * 2 + (e >> 2), j = e & 3;
            int o = g3 * 256 + 64 * w + 16 * i + lg * 4 + j;
            v[e] = src[(size_t)o * 2048 + t * 32 + b];
        }
        *reinterpret_cast<half8*>(&dst[(((size_t)(t * 2 + bh) * 4 + w) * 6 + c) * 512 + l * 8]) = v;
    }
}

// ---------------------------------------------------------------- K3: triangular GRU chains, W-persistent (unchanged from R6
// except hstore is now fp16).
__global__ __launch_bounds__(256, 1) void k_gru_f(
    const _Float16* __restrict__ gpa, const _Float16* __restrict__ gpb,
    const _Float16* __restrict__ wfa, const _Float16* __restrict__ wfb,
    const float* __restrict__ abhh, const float* __restrict__ bbhh,
    const float* __restrict__ alpha_w, const float* __restrict__ alpha_b,
    float* __restrict__ pre, _Float16* __restrict__ hstore)
{
    extern __shared__ char smem[];
    half8*    wlds = reinterpret_cast<half8*>(smem);              // [48 ot][2 kc][64 l] = 96 KB
    _Float16* hsp  = reinterpret_cast<_Float16*>(smem + 98304);   // [2 buf][16 rows][256] = 16 KB
    float*    red  = reinterpret_cast<float*>(smem + 98304 + 16384);  // [2][16][4]

    int bid = blockIdx.x;
    int g   = bid / 126;
    int rr_ = bid % 126;
    int p   = 62 - (rr_ >> 1);
    int bh  = rr_ & 1;
    int tid = threadIdx.x;
    int w = tid >> 6, l = tid & 63, lg = l >> 4, lr = l & 15;
    const _Float16* gp  = g ? gpb : gpa;
    const _Float16* wf  = g ? wfb : wfa;
    const float*    bhh = g ? bbhh : abhh;

    half8 wreg[3][4][6];
    #pragma unroll
    for (int g3 = 0; g3 < 3; ++g3)
        #pragma unroll
        for (int i = 0; i < 4; ++i) {
            int ot = g3 * 16 + 4 * w + i;
            #pragma unroll
            for (int kc = 0; kc < 6; ++kc)
                wreg[g3][i][kc] = *reinterpret_cast<const half8*>(&wf[((size_t)(ot * 8 + kc) * 64 + l) * 8]);
        }
    #pragma unroll
    for (int q = 0; q < 24; ++q) {
        int idx = q * 256 + tid;
        int ot = idx >> 7, kcs = (idx >> 6) & 1, l2 = idx & 63;
        wlds[idx] = *reinterpret_cast<const half8*>(&wf[((size_t)(ot * 8 + 6 + kcs) * 64 + l2) * 8]);
    }
    float bhn[4][4], awv[4][4];
    #pragma unroll
    for (int i = 0; i < 4; ++i)
        #pragma unroll
        for (int j = 0; j < 4; ++j) {
            int d = 64 * w + 16 * i + lg * 4 + j;
            bhn[i][j] = bhh[512 + d];
            awv[i][j] = alpha_w[d];
        }
    float ab = alpha_b[0];
    float hreg[4][4];
    #pragma unroll
    for (int i = 0; i < 4; ++i)
        #pragma unroll
        for (int j = 0; j < 4; ++j) hreg[i][j] = 0.f;
    __syncthreads();

    size_t tri = (size_t)p * (p + 1) / 2;

    for (int k = 0; k <= p; ++k) {
        int t_in = p - k;
        int wr = k & 1, rb = wr ^ 1;
        if (k > 0 && g == 0 && tid < 16) {
            float s = red[((rb * 16 + tid) << 2) + 0] + red[((rb * 16 + tid) << 2) + 1]
                    + red[((rb * 16 + tid) << 2) + 2] + red[((rb * 16 + tid) << 2) + 3];
            pre[((size_t)p * T_ + (t_in + 1)) * B_ + bh * 16 + tid] = 0.5f * s + ab;
        }
        half8 gch[6];
        {
            const _Float16* gq = gp + (((size_t)(t_in * 2 + bh) * 4 + w) * 6) * 512 + l * 8;
            #pragma unroll
            for (int c = 0; c < 6; ++c)
                gch[c] = *reinterpret_cast<const half8*>(gq + (size_t)c * 512);
        }
        f32x4 acc[3][4];
        #pragma unroll
        for (int g3 = 0; g3 < 3; ++g3)
            #pragma unroll
            for (int i = 0; i < 4; ++i)
                #pragma unroll
                for (int j = 0; j < 4; ++j) acc[g3][i][j] = 0.f;
        if (k > 0) {
            half8 bhv[2];
            {
                int cb = (lg * 8) ^ ((lr & 7) << 3);
                bhv[0] = *reinterpret_cast<const half8*>(&hsp[(rb * 16 + lr) * 256 + cb]);
            }
            #pragma unroll
            for (int kc = 0; kc < 8; ++kc) {
                if (kc < 7) {
                    int cb = ((kc + 1) * 32 + lg * 8) ^ ((lr & 7) << 3);
                    bhv[(kc + 1) & 1] = *reinterpret_cast<const half8*>(&hsp[(rb * 16 + lr) * 256 + cb]);
                }
                if (kc < 6) {
                    #pragma unroll
                    for (int g3 = 0; g3 < 3; ++g3)
                        #pragma unroll
                        for (int i = 0; i < 4; ++i)
                            acc[g3][i] = __builtin_amdgcn_mfma_f32_16x16x32_f16(
                                wreg[g3][i][kc], bhv[kc & 1], acc[g3][i], 0, 0, 0);
                } else {
                    #pragma unroll
                    for (int g3 = 0; g3 < 3; ++g3)
                        #pragma unroll
                        for (int i = 0; i < 4; ++i) {
                            half8 wlv = wlds[((g3 * 16 + 4 * w + i) * 2 + (kc - 6)) * 64 + l];
                            acc[g3][i] = __builtin_amdgcn_mfma_f32_16x16x32_f16(
                                wlv, bhv[kc & 1], acc[g3][i], 0, 0, 0);
                        }
                }
            }
        }
        _Float16* hdst = hstore + ((tri + (size_t)k) * B_ + bh * 16 + lr) * (size_t)E_ + 64 * w + lg * 4;
        #pragma unroll
        for (int i = 0; i < 4; ++i) {
            half4 hh;
            #pragma unroll
            for (int j = 0; j < 4; ++j) {
                int c = i >> 1, e = (i & 1) * 4 + j;
                float rg = sigmoidf_(acc[0][i][j] + (float)gch[c][e]);
                float zg = sigmoidf_(acc[1][i][j] + (float)gch[2 + c][e]);
                float ng = tanhfast_((float)gch[4 + c][e] + rg * (acc[2][i][j] + bhn[i][j]));
                float h  = (1.f - zg) * ng + zg * hreg[i][j];
                hreg[i][j] = h;
                hh[j] = (_Float16)h;
            }
            int ce = (64 * w + 16 * i + lg * 4) ^ ((lr & 7) << 3);
            *reinterpret_cast<half4*>(&hsp[(wr * 16 + lr) * 256 + ce]) = hh;
            if (g) *reinterpret_cast<half4*>(hdst + 16 * i) = hh;
        }
        if (!g) {
            float pa = 0.f;
            #pragma unroll
            for (int i = 0; i < 4; ++i)
                #pragma unroll
                for (int j = 0; j < 4; ++j) pa += hreg[i][j] * awv[i][j];
            pa += __shfl_xor(pa, 16, 64);
            pa += __shfl_xor(pa, 32, 64);
            if (l < 16) red[((wr * 16 + l) << 2) + w] = pa;
        }
        barrier_lds_();
    }
    if (g == 0 && tid < 16) {
        int wl = p & 1;
        float s = red[((wl * 16 + tid) << 2) + 0] + red[((wl * 16 + tid) << 2) + 1]
                + red[((wl * 16 + tid) << 2) + 2] + red[((wl * 16 + tid) << 2) + 3];
        pre[((size_t)p * T_ + 0) * B_ + bh * 16 + tid] = 0.5f * s + ab;
    }
}

// ---------------------------------------------------------------- K4: softmax over k<=p per (p,b)
__global__ __launch_bounds__(64) void k_softmax(const float* __restrict__ pre, float* __restrict__ alpha) {
    int p = blockIdx.x >> 5, b = blockIdx.x & 31;
    int k = threadIdx.x;
    float v = (k <= p) ? pre[((size_t)p * T_ + k) * B_ + b] : -3.4e38f;
    float m = v;
    #pragma unroll
    for (int off = 32; off > 0; off >>= 1) m = fmaxf(m, __shfl_xor(m, off, 64));
    float e = (k <= p) ? __expf(v - m) : 0.f;
    float s = e;
    #pragma unroll
    for (int off = 32; off > 0; off >>= 1) s += __shfl_xor(s, off, 64);
    if (k <= p) alpha[((size_t)p * T_ + k) * B_ + b] = e / s;
}

// ---------------------------------------------------------------- K5: beta GEMM (MFMA) + U in-place + pred.
// Persistent: 252 blocks x 8 pairs. Per pair (p,b): stage H (reversed, swizzled) + ewh into
// LDS; beta = tanh(H @ (0.5 beta_w)^T + beta_b) via MFMA (A=bwf in regs); U = alpha*beta
// overwrites hU rows (all H reads staged first); pred = sum U*ewh reduced block-wide.
__global__ __launch_bounds__(256, 1) void k_beta2(
    _Float16* __restrict__ hU,
    const _Float16* __restrict__ bwf,
    const float* __restrict__ beta_b,
    const float* __restrict__ alpha,
    const _Float16* __restrict__ ewh,
    const float* __restrict__ out_b,
    float* __restrict__ outp)
{
    extern __shared__ char smem[];
    _Float16* hs   = reinterpret_cast<_Float16*>(smem);           // [64][256] swizzled
    _Float16* es   = reinterpret_cast<_Float16*>(smem + 32768);   // [64][256] swizzled
    float*    alds = reinterpret_cast<float*>(smem + 65536);      // [64]
    float*    red  = reinterpret_cast<float*>(smem + 65536 + 256);// [4]
    int tid = threadIdx.x;
    int w = tid >> 6, l = tid & 63, lg = l >> 4, lr = l & 15;

    half8 aw[4][8];
    #pragma unroll
    for (int ot = 0; ot < 4; ++ot)
        #pragma unroll
        for (int kc = 0; kc < 8; ++kc)
            aw[ot][kc] = *reinterpret_cast<const half8*>(&bwf[(((size_t)(4 * w + ot) * 8 + kc) * 64 + l) * 8]);
    float bb[4][4];
    #pragma unroll
    for (int ot = 0; ot < 4; ++ot)
        #pragma unroll
        for (int j = 0; j < 4; ++j)
            bb[ot][j] = beta_b[(4 * w + ot) * 16 + lg * 4 + j];
    float ob = out_b[0];

    for (int it = 0; it < 8; ++it) {
        int pair = blockIdx.x * 8 + it;
        int p = pair >> 5, b = pair & 31;
        size_t tri = (size_t)p * (p + 1) / 2;
        // ---- stage
        {
            int kr = tid >> 5, l32 = tid & 31, e0 = l32 * 8;
            #pragma unroll
            for (int q = 0; q < 8; ++q) {
                int k = q * 8 + kr;
                int sw = e0 ^ ((k & 7) << 3);
                half8 hv, evv;
                if (k <= p) {
                    hv  = *reinterpret_cast<const half8*>(&hU[((tri + (size_t)(p - k)) * B_ + b) * 256 + e0]);
                    evv = *reinterpret_cast<const half8*>(&ewh[((size_t)k * B_ + b) * 256 + e0]);
                } else {
                    #pragma unroll
                    for (int j = 0; j < 8; ++j) { hv[j] = (_Float16)0.f; evv[j] = (_Float16)0.f; }
                }
                *reinterpret_cast<half8*>(&hs[k * 256 + sw]) = hv;
                *reinterpret_cast<half8*>(&es[k * 256 + sw]) = evv;
            }
        }
        if (tid < 64) alds[tid] = (tid <= p) ? alpha[((size_t)p * T_ + tid) * B_ + b] : 0.f;
        __syncthreads();
        // ---- GEMM1
        f32x4 acc[4][4];
        #pragma unroll
        for (int ot = 0; ot < 4; ++ot)
            #pragma unroll
            for (int rt = 0; rt < 4; ++rt)
                #pragma unroll
                for (int j = 0; j < 4; ++j) acc[ot][rt][j] = bb[ot][j];
        #pragma unroll
        for (int kc = 0; kc < 8; ++kc) {
            half8 hb[4];
            #pragma unroll
            for (int rt = 0; rt < 4; ++rt)
                hb[rt] = *reinterpret_cast<const half8*>(&hs[(rt * 16 + lr) * 256 + ((kc * 32 + lg * 8) ^ ((lr & 7) << 3))]);
            #pragma unroll
            for (int ot = 0; ot < 4; ++ot)
                #pragma unroll
                for (int rt = 0; rt < 4; ++rt)
                    acc[ot][rt] = __builtin_amdgcn_mfma_f32_16x16x32_f16(aw[ot][kc], hb[rt], acc[ot][rt], 0, 0, 0);
        }
        // ---- epilogue: U + pred
        float pv = 0.f;
        #pragma unroll
        for (int ot = 0; ot < 4; ++ot)
            #pragma unroll
            for (int rt = 0; rt < 4; ++rt) {
                int k = rt * 16 + lr;
                float al = alds[k];
                int d0 = (4 * w + ot) * 16 + lg * 4;
                half4 ev4 = *reinterpret_cast<const half4*>(&es[k * 256 + (d0 ^ ((lr & 7) << 3))]);
                half4 uv;
                #pragma unroll
                for (int j = 0; j < 4; ++j) {
                    float bet = tanhfast_(acc[ot][rt][j]);
                    float u = al * bet;
                    uv[j] = (_Float16)u;
                    pv += u * (float)ev4[j];
                }
                if (k <= p)
                    *reinterpret_cast<half4*>(&hU[((tri + (size_t)k) * B_ + b) * 256 + d0]) = uv;
            }
        #pragma unroll
        for (int off = 1; off < 64; off <<= 1) pv += __shfl_xor(pv, off, 64);
        if (l == 0) red[w] = pv;
        __syncthreads();
        if (tid == 0) outp[(size_t)b * P_ + p] = red[0] + red[1] + red[2] + red[3] + ob;
        __syncthreads();
    }
}

// ---------------------------------------------------------------- K6: wout GEMM (MFMA): G = U@M, out = sum_k G*x /(p+1).
__global__ __launch_bounds__(256, 1) void k_wout2(
    const _Float16* __restrict__ hU,
    const _Float16* __restrict__ mf,
    const _Float16* __restrict__ xh,
    float* __restrict__ out)
{
    extern __shared__ char smem[];
    _Float16* us = reinterpret_cast<_Float16*>(smem);           // [64][256] swizzled
    _Float16* xs = reinterpret_cast<_Float16*>(smem + 32768);   // [64][256] swizzled
    int tid = threadIdx.x;
    int w = tid >> 6, l = tid & 63, lg = l >> 4, lr = l & 15;

    half8 aw[4][8];
    #pragma unroll
    for (int ot = 0; ot < 4; ++ot)
        #pragma unroll
        for (int kc = 0; kc < 8; ++kc)
            aw[ot][kc] = *reinterpret_cast<const half8*>(&mf[(((size_t)(4 * w + ot) * 8 + kc) * 64 + l) * 8]);

    for (int it = 0; it < 8; ++it) {
        int pair = blockIdx.x * 8 + it;
        int p = pair >> 5, b = pair & 31;
        size_t tri = (size_t)p * (p + 1) / 2;
        {
            int kr = tid >> 5, l32 = tid & 31, e0 = l32 * 8;
            #pragma unroll
            for (int q = 0; q < 8; ++q) {
                int k = q * 8 + kr;
                int sw = e0 ^ ((k & 7) << 3);
                half8 uv;
                if (k <= p) {
                    uv = *reinterpret_cast<const half8*>(&hU[((tri + (size_t)k) * B_ + b) * 256 + e0]);
                } else {
                    #pragma unroll
                    for (int j = 0; j < 8; ++j) uv[j] = (_Float16)0.f;
                }
                *reinterpret_cast<half8*>(&us[k * 256 + sw]) = uv;
                *reinterpret_cast<half8*>(&xs[k * 256 + sw]) =
                    *reinterpret_cast<const half8*>(&xh[((size_t)b * T_ + k) * 256 + e0]);
            }
        }
        __syncthreads();
        f32x4 acc[4][4];
        #pragma unroll
        for (int ot = 0; ot < 4; ++ot)
            #pragma unroll
            for (int rt = 0; rt < 4; ++rt)
                #pragma unroll
                for (int j = 0; j < 4; ++j) acc[ot][rt][j] = 0.f;
        #pragma unroll
        for (int kc = 0; kc < 8; ++kc) {
            half8 ub[4];
            #pragma unroll
            for (int rt = 0; rt < 4; ++rt)
                ub[rt] = *reinterpret_cast<const half8*>(&us[(rt * 16 + lr) * 256 + ((kc * 32 + lg * 8) ^ ((lr & 7) << 3))]);
            #pragma unroll
            for (int ot = 0; ot < 4; ++ot)
                #pragma unroll
                for (int rt = 0; rt < 4; ++rt)
                    acc[ot][rt] = __builtin_amdgcn_mfma_f32_16x16x32_f16(aw[ot][kc], ub[rt], acc[ot][rt], 0, 0, 0);
        }
        float r[4][4];
        #pragma unroll
        for (int ot = 0; ot < 4; ++ot)
            #pragma unroll
            for (int j = 0; j < 4; ++j) r[ot][j] = 0.f;
        #pragma unroll
        for (int ot = 0; ot < 4; ++ot)
            #pragma unroll
            for (int rt = 0; rt < 4; ++rt) {
                int k = rt * 16 + lr;
                int i0 = (4 * w + ot) * 16 + lg * 4;
                half4 xv4 = *reinterpret_cast<const half4*>(&xs[k * 256 + (i0 ^ ((lr & 7) << 3))]);
                #pragma unroll
                for (int j = 0; j < 4; ++j) r[ot][j] += acc[ot][rt][j] * (float)xv4[j];
            }
        #pragma unroll
        for (int off = 1; off < 16; off <<= 1)
            #pragma unroll
            for (int ot = 0; ot < 4; ++ot)
                #pragma unroll
                for (int j = 0; j < 4; ++j) r[ot][j] += __shfl_xor(r[ot][j], off, 64);
        if (lr == 0) {
            float inv = 1.f / (float)(p + 1);
            #pragma unroll
            for (int ot = 0; ot < 4; ++ot) {
                f32x4 v;
                #pragma unroll
                for (int j = 0; j < 4; ++j) v[j] = r[ot][j] * inv;
                *reinterpret_cast<f32x4*>(&out[2016 + ((size_t)b * P_ + p) * 256 + (4 * w + ot) * 16 + lg * 4]) = v;
            }
        }
        __syncthreads();
    }
}

// ---------------------------------------------------------------- host
extern "C" void kernel_launch(void* const* d_in, const int* in_sizes, int n_in,
                              void* d_out, int out_size, void* d_ws, size_t ws_size,
                              hipStream_t stream) {
    const float* x       = (const float*)d_in[0];
    const float* emb_w   = (const float*)d_in[1];
    const float* emb_b   = (const float*)d_in[2];
    const float* a_wih   = (const float*)d_in[3];
    const float* a_whh   = (const float*)d_in[4];
    const float* a_bih   = (const float*)d_in[5];
    const float* a_bhh   = (const float*)d_in[6];
    const float* b_wih   = (const float*)d_in[7];
    const float* b_whh   = (const float*)d_in[8];
    const float* b_bih   = (const float*)d_in[9];
    const float* b_bhh   = (const float*)d_in[10];
    const float* alpha_w = (const float*)d_in[11];
    const float* alpha_b = (const float*)d_in[12];
    const float* beta_w  = (const float*)d_in[13];
    const float* beta_b  = (const float*)d_in[14];
    const float* out_w   = (const float*)d_in[15];
    const float* out_b   = (const float*)d_in[16];
    float* out = (float*)d_out;

    float* ws = (float*)d_ws;
    // ws layout (floats), total ~13.0M floats = 51.9 MB
    float* emb      = ws;                            // 524288
    _Float16* ewh   = (_Float16*)(emb + 524288);     // 524288 h = 262144 f
    _Float16* giTa  = (_Float16*)(emb + 786432);     // 786432 f
    _Float16* giTb  = giTa + 1572864;                // 786432 f
    _Float16* gpa   = giTb + 1572864;                // 786432 f
    _Float16* gpb   = gpa  + 1572864;                // 786432 f
    float* pre      = (float*)(gpb + 1572864);       // 129024
    float* alpha    = pre   + 129024;                // 129024
    _Float16* wfa   = (_Float16*)(alpha + 129024);   // 196608 h = 98304 f
    _Float16* wfb   = wfa + 196608;                  // 98304 f
    _Float16* bwf   = wfb + 196608;                  // 65536 h = 32768 f
    _Float16* mf    = bwf + 65536;                   // 65536 h = 32768 f
    _Float16* xh    = mf  + 65536;                   // 524288 h = 262144 f
    _Float16* hU    = xh  + 524288;                  // 16515072 h = 8257536 f

    const int GRU_LDS = 98304 + 16384 + 512;         // 115200 B
    (void)hipFuncSetAttribute((const void*)k_gru_f,
                              hipFuncAttributeMaxDynamicSharedMemorySize, GRU_LDS);
    const int B2_LDS = 65536 + 256 + 64;
    (void)hipFuncSetAttribute((const void*)k_beta2,
                              hipFuncAttributeMaxDynamicSharedMemorySize, B2_LDS);
    const int W2_LDS = 65536;
    (void)hipFuncSetAttribute((const void*)k_wout2,
                              hipFuncAttributeMaxDynamicSharedMemorySize, W2_LDS);

    k_emb<<<2048, 256, 0, stream>>>(x, emb_w, emb_b, out_w, emb, ewh);
    k_gates<<<256, 256, 0, stream>>>(emb, a_wih, a_bih, a_bhh, b_wih, b_bih, b_bhh, giTa, giTb);
    k_wfrag<<<384, 64, 0, stream>>>(a_whh, wfa, 1.0f);
    k_wfrag<<<384, 64, 0, stream>>>(b_whh, wfb, 1.0f);
    k_wfrag<<<128, 64, 0, stream>>>(beta_w, bwf, 0.5f);
    k_mfrag<<<128, 64, 0, stream>>>(emb_w, out_w, mf);
    k_xh<<<2048, 256, 0, stream>>>(x, xh);
    k_gipack<<<256, 256, 0, stream>>>(giTa, giTb, gpa, gpb);
    k_gru_f<<<252, 256, GRU_LDS, stream>>>(gpa, gpb, wfa, wfb, a_bhh, b_bhh,
                                           alpha_w, alpha_b, pre, hU);
    k_softmax<<<2016, 64, 0, stream>>>(pre, alpha);
    k_beta2<<<252, 256, B2_LDS, stream>>>(hU, bwf, beta_b, alpha, ewh, out_b, out);
    k_wout2<<<252, 256, W2_LDS, stream>>>(hU, mf, xh, out);
}

// Round 8
// 444.110 us; speedup vs baseline: 2.5726x; 1.1392x over previous
//
#include <hip/hip_runtime.h>
#include <math.h>

// Problem constants: B=32, T=64, I=E=Ha=Hb=256, O=1, P=T-1=63
#define B_   32
#define T_   64
#define P_   63
#define E_   256
#define G3_  768

typedef _Float16 half8 __attribute__((ext_vector_type(8)));
typedef _Float16 half4 __attribute__((ext_vector_type(4)));
typedef float    f32x4 __attribute__((ext_vector_type(4)));

__device__ __forceinline__ float sigmoidf_(float x) { return 1.0f / (1.0f + __expf(-x)); }
__device__ __forceinline__ float tanhfast_(float x) { float e = __expf(2.0f*x); return 1.0f - 2.0f/(e + 1.0f); }

// Barrier WITHOUT vmcnt drain: only LDS ops must be visible across it.
__device__ __forceinline__ void barrier_lds_() {
    asm volatile("" ::: "memory");
    asm volatile("s_waitcnt lgkmcnt(0)" ::: "memory");
    __builtin_amdgcn_s_barrier();
    asm volatile("" ::: "memory");
}

// ---------------------------------------------------------------- K1: emb[t,b,e] = emb_w @ x[b,t,:] + emb_b ; ewh = fp16(emb*out_w)
__global__ __launch_bounds__(256) void k_emb(const float* __restrict__ x,
                                             const float* __restrict__ emb_w,
                                             const float* __restrict__ emb_b,
                                             const float* __restrict__ out_w,
                                             float* __restrict__ emb,
                                             _Float16* __restrict__ ewh) {
    int t = blockIdx.x >> 5, b = blockIdx.x & 31;
    int tid = threadIdx.x;
    __shared__ float xr[E_];
    xr[tid] = x[((size_t)b * T_ + t) * E_ + tid];
    __syncthreads();
    const float* wr = emb_w + (size_t)tid * E_;
    float acc = emb_b[tid];
    for (int c = 0; c < 256; c += 4) {
        float4 wv = *reinterpret_cast<const float4*>(wr + c);
        float4 xv = *reinterpret_cast<const float4*>(&xr[c]);
        acc += wv.x * xv.x + wv.y * xv.y + wv.z * xv.z + wv.w * xv.w;
    }
    size_t o = ((size_t)t * B_ + b) * E_ + tid;
    emb[o] = acc;
    ewh[o] = (_Float16)(acc * out_w[tid]);
}

// ---------------------------------------------------------------- K2: input gates -> fp16, transposed [o][r]
__global__ __launch_bounds__(256) void k_gates(const float* __restrict__ emb,
                                               const float* __restrict__ awih, const float* __restrict__ abih,
                                               const float* __restrict__ abhh,
                                               const float* __restrict__ bwih, const float* __restrict__ bbih,
                                               const float* __restrict__ bbhh,
                                               _Float16* __restrict__ giTa, _Float16* __restrict__ giTb) {
    int r0 = blockIdx.x * 8;
    int tid = threadIdx.x;
    __shared__ float es[8][E_];
    for (int rr = 0; rr < 8; ++rr) es[rr][tid] = emb[(size_t)(r0 + rr) * E_ + tid];
    __syncthreads();
    for (int gs = 0; gs < 6; ++gs) {
        const float* W    = (gs < 3) ? awih : bwih;
        const float* bih  = (gs < 3) ? abih : bbih;
        const float* bhh  = (gs < 3) ? abhh : bbhh;
        _Float16* giT     = (gs < 3) ? giTa : giTb;
        int gate = gs % 3;
        int grow = gate * 256 + tid;
        const float* wr = W + (size_t)grow * E_;
        float acc[8];
        #pragma unroll
        for (int rr = 0; rr < 8; ++rr) acc[rr] = 0.f;
        for (int c = 0; c < 256; c += 4) {
            float4 wv = *reinterpret_cast<const float4*>(wr + c);
            #pragma unroll
            for (int rr = 0; rr < 8; ++rr) {
                float4 ev = *reinterpret_cast<const float4*>(&es[rr][c]);
                acc[rr] += wv.x * ev.x + wv.y * ev.y + wv.z * ev.z + wv.w * ev.w;
            }
        }
        float bv = bih[grow] + ((gate < 2) ? bhh[grow] : 0.f);
        _Float16* dst = giT + (size_t)grow * 2048 + r0;
        #pragma unroll
        for (int rr = 0; rr < 8; ++rr) dst[rr] = (_Float16)(acc[rr] + bv);
    }
}

// ---------------------------------------------------------------- K2b: row-major fp32 W -> fp16 MFMA A-fragments (with scale)
__global__ __launch_bounds__(64) void k_wfrag(const float* __restrict__ whh, _Float16* __restrict__ wf, float scale) {
    int ot = blockIdx.x >> 3, kc = blockIdx.x & 7, l = threadIdx.x;
    int orow = ot * 16 + (l & 15);
    int c0   = kc * 32 + (l >> 4) * 8;
    half8 v;
    #pragma unroll
    for (int j = 0; j < 8; ++j) v[j] = (_Float16)(scale * whh[(size_t)orow * 256 + c0 + j]);
    *reinterpret_cast<half8*>(&wf[((size_t)(ot * 8 + kc) * 64 + l) * 8]) = v;
}

// ---------------------------------------------------------------- K2m: M^T A-frags: A[row=i][k=e] = out_w[e]*emb_w[e][i]
__global__ __launch_bounds__(64) void k_mfrag(const float* __restrict__ emb_w, const float* __restrict__ out_w,
                                              _Float16* __restrict__ mf) {
    int ot = blockIdx.x >> 3, kc = blockIdx.x & 7, l = threadIdx.x;
    int i  = ot * 16 + (l & 15);
    int e0 = kc * 32 + (l >> 4) * 8;
    half8 v;
    #pragma unroll
    for (int j = 0; j < 8; ++j) v[j] = (_Float16)(out_w[e0 + j] * emb_w[(size_t)(e0 + j) * 256 + i]);
    *reinterpret_cast<half8*>(&mf[((size_t)(ot * 8 + kc) * 64 + l) * 8]) = v;
}

// ---------------------------------------------------------------- K2x: x -> fp16 copy
__global__ __launch_bounds__(256) void k_xh(const float* __restrict__ x, _Float16* __restrict__ xh) {
    int i = blockIdx.x * 256 + threadIdx.x;
    xh[i] = (_Float16)x[i];
}

// ---------------------------------------------------------------- K2c: pack gi for the 8-wave / 16-batch k_gru_f.
// gp[(((t*2+bh)*8 + w)*3 + g3)*512 + l*8 + e]: gate g3, dim = 32w + 16*(e>>2) + lg*4 + (e&3),
// batch = bh*16 + lr. One fully-coalesced 16B load per (thread, gate) per step.
__global__ __launch_bounds__(512) void k_gipack(const _Float16* __restrict__ gA, const _Float16* __restrict__ gB,
                                                _Float16* __restrict__ pA, _Float16* __restrict__ pB) {
    int bid = blockIdx.x;
    int g = bid >> 7, t = (bid >> 1) & 63, bh = bid & 1;
    const _Float16* src = g ? gB : gA;
    _Float16*       dst = g ? pB : pA;
    int tid = threadIdx.x, w = tid >> 6, l = tid & 63, lg = l >> 4, lr = l & 15;
    int b = bh * 16 + lr;
    #pragma unroll
    for (int c = 0; c < 3; ++c) {
        half8 v;
        #pragma unroll
        for (int e = 0; e < 8; ++e) {
            int i = e >> 2, j = e & 3;
            int o = c * 256 + 32 * w + 16 * i + lg * 4 + j;
            v[e] = src[(size_t)o * 2048 + t * 32 + b];
        }
        *reinterpret_cast<half8*>(&dst[(((size_t)(t * 2 + bh) * 8 + w) * 3 + c) * 512 + l * 8]) = v;
    }
}

// ---------------------------------------------------------------- K3: triangular GRU chains, 8-wave / 2 waves-per-SIMD.
// block = (p desc, g, bh): 252 blocks x 512 threads. Wave w owns out-dims [32w,32w+32) per
// gate (2 MFMA tiles); 16 batch rows. W_hh: kc 0..5 in regs (144 VGPR), kc 6..7 in LDS
// (96 KB, filled once). Same arithmetic as R7; doubled SIMD occupancy for MFMA/VALU/LDS
// overlap across the 2 resident waves.
__global__ __launch_bounds__(512, 2) void k_gru_f(
    const _Float16* __restrict__ gpa, const _Float16* __restrict__ gpb,
    const _Float16* __restrict__ wfa, const _Float16* __restrict__ wfb,
    const float* __restrict__ abhh, const float* __restrict__ bbhh,
    const float* __restrict__ alpha_w, const float* __restrict__ alpha_b,
    float* __restrict__ pre, _Float16* __restrict__ hstore)
{
    extern __shared__ char smem[];
    half8*    wlds = reinterpret_cast<half8*>(smem);              // [48 ot][2 kc][64 l] = 96 KB
    _Float16* hsp  = reinterpret_cast<_Float16*>(smem + 98304);   // [2 buf][16 rows][256] = 16 KB
    float*    red  = reinterpret_cast<float*>(smem + 98304 + 16384);  // [2][16][8] = 1 KB

    int bid = blockIdx.x;
    int p   = 62 - (bid >> 2);
    int g   = (bid >> 1) & 1;
    int bh  = bid & 1;
    int tid = threadIdx.x;
    int w = tid >> 6, l = tid & 63, lg = l >> 4, lr = l & 15;
    const _Float16* gp  = g ? gpb : gpa;
    const _Float16* wf  = g ? wfb : wfa;
    const float*    bhh = g ? bbhh : abhh;

    // ---- prologue: W kc 0..5 into registers (once)
    half8 wreg[3][2][6];
    #pragma unroll
    for (int g3 = 0; g3 < 3; ++g3)
        #pragma unroll
        for (int i = 0; i < 2; ++i) {
            int ot = g3 * 16 + 2 * w + i;
            #pragma unroll
            for (int kc = 0; kc < 6; ++kc)
                wreg[g3][i][kc] = *reinterpret_cast<const half8*>(&wf[((size_t)(ot * 8 + kc) * 64 + l) * 8]);
        }
    // ---- prologue: W kc 6..7 into LDS (once): 48*2*64 = 6144 half8, 12 per thread
    #pragma unroll
    for (int q = 0; q < 12; ++q) {
        int idx = q * 512 + tid;
        int ot = idx >> 7, kcs = (idx >> 6) & 1, l2 = idx & 63;
        wlds[idx] = *reinterpret_cast<const half8*>(&wf[((size_t)(ot * 8 + 6 + kcs) * 64 + l2) * 8]);
    }
    float bhn[2][4], awv[2][4];
    #pragma unroll
    for (int i = 0; i < 2; ++i)
        #pragma unroll
        for (int j = 0; j < 4; ++j) {
            int d = 32 * w + 16 * i + lg * 4 + j;
            bhn[i][j] = bhh[512 + d];
            awv[i][j] = alpha_w[d];
        }
    float ab = alpha_b[0];
    float hreg[2][4];
    #pragma unroll
    for (int i = 0; i < 2; ++i)
        #pragma unroll
        for (int j = 0; j < 4; ++j) hreg[i][j] = 0.f;
    __syncthreads();   // wlds visible (one-time full sync)

    size_t tri = (size_t)p * (p + 1) / 2;

    for (int k = 0; k <= p; ++k) {
        int t_in = p - k;
        int wr = k & 1, rb = wr ^ 1;
        // ---- drain step k-1's pre (g=0)
        if (k > 0 && g == 0 && tid < 16) {
            float s = 0.f;
            #pragma unroll
            for (int q = 0; q < 8; ++q) s += red[(rb * 16 + tid) * 8 + q];
            pre[((size_t)p * T_ + (t_in + 1)) * B_ + bh * 16 + tid] = 0.5f * s + ab;
        }
        // ---- gi loads (consumed at nonlinearity; covered by MFMA phase)
        half8 gch[3];
        {
            const _Float16* gq = gp + (((size_t)(t_in * 2 + bh) * 8 + w) * 3) * 512 + l * 8;
            #pragma unroll
            for (int c = 0; c < 3; ++c)
                gch[c] = *reinterpret_cast<const half8*>(gq + (size_t)c * 512);
        }
        // ---- MFMA: acc = W @ h (skip at k=0)
        f32x4 acc[3][2];
        #pragma unroll
        for (int g3 = 0; g3 < 3; ++g3)
            #pragma unroll
            for (int i = 0; i < 2; ++i)
                #pragma unroll
                for (int j = 0; j < 4; ++j) acc[g3][i][j] = 0.f;
        if (k > 0) {
            half8 bhv[2];
            {
                int cb = (lg * 8) ^ ((lr & 7) << 3);
                bhv[0] = *reinterpret_cast<const half8*>(&hsp[(rb * 16 + lr) * 256 + cb]);
            }
            #pragma unroll
            for (int kc = 0; kc < 8; ++kc) {
                if (kc < 7) {
                    int cb = ((kc + 1) * 32 + lg * 8) ^ ((lr & 7) << 3);
                    bhv[(kc + 1) & 1] = *reinterpret_cast<const half8*>(&hsp[(rb * 16 + lr) * 256 + cb]);
                }
                if (kc < 6) {
                    #pragma unroll
                    for (int g3 = 0; g3 < 3; ++g3)
                        #pragma unroll
                        for (int i = 0; i < 2; ++i)
                            acc[g3][i] = __builtin_amdgcn_mfma_f32_16x16x32_f16(
                                wreg[g3][i][kc], bhv[kc & 1], acc[g3][i], 0, 0, 0);
                } else {
                    #pragma unroll
                    for (int g3 = 0; g3 < 3; ++g3)
                        #pragma unroll
                        for (int i = 0; i < 2; ++i) {
                            half8 wlv = wlds[((g3 * 16 + 2 * w + i) * 2 + (kc - 6)) * 64 + l];
                            acc[g3][i] = __builtin_amdgcn_mfma_f32_16x16x32_f16(
                                wlv, bhv[kc & 1], acc[g3][i], 0, 0, 0);
                        }
                }
            }
        }
        // ---- nonlinearity + state update + fp16 LDS write (+ hstore for g=1)
        _Float16* hdst = hstore + ((tri + (size_t)k) * B_ + bh * 16 + lr) * (size_t)E_ + 32 * w + lg * 4;
        #pragma unroll
        for (int i = 0; i < 2; ++i) {
            half4 hh;
            #pragma unroll
            for (int j = 0; j < 4; ++j) {
                int e = i * 4 + j;
                float rg = sigmoidf_(acc[0][i][j] + (float)gch[0][e]);
                float zg = sigmoidf_(acc[1][i][j] + (float)gch[1][e]);
                float ng = tanhfast_((float)gch[2][e] + rg * (acc[2][i][j] + bhn[i][j]));
                float h  = (1.f - zg) * ng + zg * hreg[i][j];
                hreg[i][j] = h;
                hh[j] = (_Float16)h;
            }
            int ce = (32 * w + 16 * i + lg * 4) ^ ((lr & 7) << 3);
            *reinterpret_cast<half4*>(&hsp[(wr * 16 + lr) * 256 + ce]) = hh;
            if (g) *reinterpret_cast<half4*>(hdst + 16 * i) = hh;
        }
        if (!g) {
            float pa = 0.f;
            #pragma unroll
            for (int i = 0; i < 2; ++i)
                #pragma unroll
                for (int j = 0; j < 4; ++j) pa += hreg[i][j] * awv[i][j];
            pa += __shfl_xor(pa, 16, 64);
            pa += __shfl_xor(pa, 32, 64);
            if (l < 16) red[(wr * 16 + l) * 8 + w] = pa;
        }
        barrier_lds_();
    }
    // ---- epilogue: drain step p's pre
    if (g == 0 && tid < 16) {
        int wl = p & 1;
        float s = 0.f;
        #pragma unroll
        for (int q = 0; q < 8; ++q) s += red[(wl * 16 + tid) * 8 + q];
        pre[((size_t)p * T_ + 0) * B_ + bh * 16 + tid] = 0.5f * s + ab;
    }
}

// ---------------------------------------------------------------- K4: softmax over k<=p per (p,b)
__global__ __launch_bounds__(64) void k_softmax(const float* __restrict__ pre, float* __restrict__ alpha) {
    int p = blockIdx.x >> 5, b = blockIdx.x & 31;
    int k = threadIdx.x;
    float v = (k <= p) ? pre[((size_t)p * T_ + k) * B_ + b] : -3.4e38f;
    float m = v;
    #pragma unroll
    for (int off = 32; off > 0; off >>= 1) m = fmaxf(m, __shfl_xor(m, off, 64));
    float e = (k <= p) ? __expf(v - m) : 0.f;
    float s = e;
    #pragma unroll
    for (int off = 32; off > 0; off >>= 1) s += __shfl_xor(s, off, 64);
    if (k <= p) alpha[((size_t)p * T_ + k) * B_ + b] = e / s;
}

// ---------------------------------------------------------------- K5: beta GEMM (MFMA) + U in-place + pred.
__global__ __launch_bounds__(256, 1) void k_beta2(
    _Float16* __restrict__ hU,
    const _Float16* __restrict__ bwf,
    const float* __restrict__ beta_b,
    const float* __restrict__ alpha,
    const _Float16* __restrict__ ewh,
    const float* __restrict__ out_b,
    float* __restrict__ outp)
{
    extern __shared__ char smem[];
    _Float16* hs   = reinterpret_cast<_Float16*>(smem);           // [64][256] swizzled
    _Float16* es   = reinterpret_cast<_Float16*>(smem + 32768);   // [64][256] swizzled
    float*    alds = reinterpret_cast<float*>(smem + 65536);      // [64]
    float*    red  = reinterpret_cast<float*>(smem + 65536 + 256);// [4]
    int tid = threadIdx.x;
    int w = tid >> 6, l = tid & 63, lg = l >> 4, lr = l & 15;

    half8 aw[4][8];
    #pragma unroll
    for (int ot = 0; ot < 4; ++ot)
        #pragma unroll
        for (int kc = 0; kc < 8; ++kc)
            aw[ot][kc] = *reinterpret_cast<const half8*>(&bwf[(((size_t)(4 * w + ot) * 8 + kc) * 64 + l) * 8]);
    float bb[4][4];
    #pragma unroll
    for (int ot = 0; ot < 4; ++ot)
        #pragma unroll
        for (int j = 0; j < 4; ++j)
            bb[ot][j] = beta_b[(4 * w + ot) * 16 + lg * 4 + j];
    float ob = out_b[0];

    for (int it = 0; it < 8; ++it) {
        int pair = blockIdx.x * 8 + it;
        int p = pair >> 5, b = pair & 31;
        size_t tri = (size_t)p * (p + 1) / 2;
        {
            int kr = tid >> 5, l32 = tid & 31, e0 = l32 * 8;
            #pragma unroll
            for (int q = 0; q < 8; ++q) {
                int k = q * 8 + kr;
                int sw = e0 ^ ((k & 7) << 3);
                half8 hv, evv;
                if (k <= p) {
                    hv  = *reinterpret_cast<const half8*>(&hU[((tri + (size_t)(p - k)) * B_ + b) * 256 + e0]);
                    evv = *reinterpret_cast<const half8*>(&ewh[((size_t)k * B_ + b) * 256 + e0]);
                } else {
                    #pragma unroll
                    for (int j = 0; j < 8; ++j) { hv[j] = (_Float16)0.f; evv[j] = (_Float16)0.f; }
                }
                *reinterpret_cast<half8*>(&hs[k * 256 + sw]) = hv;
                *reinterpret_cast<half8*>(&es[k * 256 + sw]) = evv;
            }
        }
        if (tid < 64) alds[tid] = (tid <= p) ? alpha[((size_t)p * T_ + tid) * B_ + b] : 0.f;
        __syncthreads();
        f32x4 acc[4][4];
        #pragma unroll
        for (int ot = 0; ot < 4; ++ot)
            #pragma unroll
            for (int rt = 0; rt < 4; ++rt)
                #pragma unroll
                for (int j = 0; j < 4; ++j) acc[ot][rt][j] = bb[ot][j];
        #pragma unroll
        for (int kc = 0; kc < 8; ++kc) {
            half8 hb[4];
            #pragma unroll
            for (int rt = 0; rt < 4; ++rt)
                hb[rt] = *reinterpret_cast<const half8*>(&hs[(rt * 16 + lr) * 256 + ((kc * 32 + lg * 8) ^ ((lr & 7) << 3))]);
            #pragma unroll
            for (int ot = 0; ot < 4; ++ot)
                #pragma unroll
                for (int rt = 0; rt < 4; ++rt)
                    acc[ot][rt] = __builtin_amdgcn_mfma_f32_16x16x32_f16(aw[ot][kc], hb[rt], acc[ot][rt], 0, 0, 0);
        }
        float pv = 0.f;
        #pragma unroll
        for (int ot = 0; ot < 4; ++ot)
            #pragma unroll
            for (int rt = 0; rt < 4; ++rt) {
                int k = rt * 16 + lr;
                float al = alds[k];
                int d0 = (4 * w + ot) * 16 + lg * 4;
                half4 ev4 = *reinterpret_cast<const half4*>(&es[k * 256 + (d0 ^ ((lr & 7) << 3))]);
                half4 uv;
                #pragma unroll
                for (int j = 0; j < 4; ++j) {
                    float bet = tanhfast_(acc[ot][rt][j]);
                    float u = al * bet;
                    uv[j] = (_Float16)u;
                    pv += u * (float)ev4[j];
                }
                if (k <= p)
                    *reinterpret_cast<half4*>(&hU[((tri + (size_t)k) * B_ + b) * 256 + d0]) = uv;
            }
        #pragma unroll
        for (int off = 1; off < 64; off <<= 1) pv += __shfl_xor(pv, off, 64);
        if (l == 0) red[w] = pv;
        __syncthreads();
        if (tid == 0) outp[(size_t)b * P_ + p] = red[0] + red[1] + red[2] + red[3] + ob;
        __syncthreads();
    }
}

// ---------------------------------------------------------------- K6: wout GEMM (MFMA): G = U@M, out = sum_k G*x /(p+1).
__global__ __launch_bounds__(256, 1) void k_wout2(
    const _Float16* __restrict__ hU,
    const _Float16* __restrict__ mf,
    const _Float16* __restrict__ xh,
    float* __restrict__ out)
{
    extern __shared__ char smem[];
    _Float16* us = reinterpret_cast<_Float16*>(smem);           // [64][256] swizzled
    _Float16* xs = reinterpret_cast<_Float16*>(smem + 32768);   // [64][256] swizzled
    int tid = threadIdx.x;
    int w = tid >> 6, l = tid & 63, lg = l >> 4, lr = l & 15;

    half8 aw[4][8];
    #pragma unroll
    for (int ot = 0; ot < 4; ++ot)
        #pragma unroll
        for (int kc = 0; kc < 8; ++kc)
            aw[ot][kc] = *reinterpret_cast<const half8*>(&mf[(((size_t)(4 * w + ot) * 8 + kc) * 64 + l) * 8]);

    for (int it = 0; it < 8; ++it) {
        int pair = blockIdx.x * 8 + it;
        int p = pair >> 5, b = pair & 31;
        size_t tri = (size_t)p * (p + 1) / 2;
        {
            int kr = tid >> 5, l32 = tid & 31, e0 = l32 * 8;
            #pragma unroll
            for (int q = 0; q < 8; ++q) {
                int k = q * 8 + kr;
                int sw = e0 ^ ((k & 7) << 3);
                half8 uv;
                if (k <= p) {
                    uv = *reinterpret_cast<const half8*>(&hU[((tri + (size_t)k) * B_ + b) * 256 + e0]);
                } else {
                    #pragma unroll
                    for (int j = 0; j < 8; ++j) uv[j] = (_Float16)0.f;
                }
                *reinterpret_cast<half8*>(&us[k * 256 + sw]) = uv;
                *reinterpret_cast<half8*>(&xs[k * 256 + sw]) =
                    *reinterpret_cast<const half8*>(&xh[((size_t)b * T_ + k) * 256 + e0]);
            }
        }
        __syncthreads();
        f32x4 acc[4][4];
        #pragma unroll
        for (int ot = 0; ot < 4; ++ot)
            #pragma unroll
            for (int rt = 0; rt < 4; ++rt)
                #pragma unroll
                for (int j = 0; j < 4; ++j) acc[ot][rt][j] = 0.f;
        #pragma unroll
        for (int kc = 0; kc < 8; ++kc) {
            half8 ub[4];
            #pragma unroll
            for (int rt = 0; rt < 4; ++rt)
                ub[rt] = *reinterpret_cast<const half8*>(&us[(rt * 16 + lr) * 256 + ((kc * 32 + lg * 8) ^ ((lr & 7) << 3))]);
            #pragma unroll
            for (int ot = 0; ot < 4; ++ot)
                #pragma unroll
                for (int rt = 0; rt < 4; ++rt)
                    acc[ot][rt] = __builtin_amdgcn_mfma_f32_16x16x32_f16(aw[ot][kc], ub[rt], acc[ot][rt], 0, 0, 0);
        }
        float r[4][4];
        #pragma unroll
        for (int ot = 0; ot < 4; ++ot)
            #pragma unroll
            for (int j = 0; j < 4; ++j) r[ot][j] = 0.f;
        #pragma unroll
        for (int ot = 0; ot < 4; ++ot)
            #pragma unroll
            for (int rt = 0; rt < 4; ++rt) {
                int k = rt * 16 + lr;
                int i0 = (4 * w + ot) * 16 + lg * 4;
                half4 xv4 = *reinterpret_cast<const half4*>(&xs[k * 256 + (i0 ^ ((lr & 7) << 3))]);
                #pragma unroll
                for (int j = 0; j < 4; ++j) r[ot][j] += acc[ot][rt][j] * (float)xv4[j];
            }
        #pragma unroll
        for (int off = 1; off < 16; off <<= 1)
            #pragma unroll
            for (int ot = 0; ot < 4; ++ot)
                #pragma unroll
                for (int j = 0; j < 4; ++j) r[ot][j] += __shfl_xor(r[ot][j], off, 64);
        if (lr == 0) {
            float inv = 1.f / (float)(p + 1);
            #pragma unroll
            for (int ot = 0; ot < 4; ++ot) {
                f32x4 v;
                #pragma unroll
                for (int j = 0; j < 4; ++j) v[j] = r[ot][j] * inv;
                *reinterpret_cast<f32x4*>(&out[2016 + ((size_t)b * P_ + p) * 256 + (4 * w + ot) * 16 + lg * 4]) = v;
            }
        }
        __syncthreads();
    }
}

// ---------------------------------------------------------------- host
extern "C" void kernel_launch(void* const* d_in, const int* in_sizes, int n_in,
                              void* d_out, int out_size, void* d_ws, size_t ws_size,
                              hipStream_t stream) {
    const float* x       = (const float*)d_in[0];
    const float* emb_w   = (const float*)d_in[1];
    const float* emb_b   = (const float*)d_in[2];
    const float* a_wih   = (const float*)d_in[3];
    const float* a_whh   = (const float*)d_in[4];
    const float* a_bih   = (const float*)d_in[5];
    const float* a_bhh   = (const float*)d_in[6];
    const float* b_wih   = (const float*)d_in[7];
    const float* b_whh   = (const float*)d_in[8];
    const float* b_bih   = (const float*)d_in[9];
    const float* b_bhh   = (const float*)d_in[10];
    const float* alpha_w = (const float*)d_in[11];
    const float* alpha_b = (const float*)d_in[12];
    const float* beta_w  = (const float*)d_in[13];
    const float* beta_b  = (const float*)d_in[14];
    const float* out_w   = (const float*)d_in[15];
    const float* out_b   = (const float*)d_in[16];
    float* out = (float*)d_out;

    float* ws = (float*)d_ws;
    float* emb      = ws;                            // 524288
    _Float16* ewh   = (_Float16*)(emb + 524288);     // 262144 f
    _Float16* giTa  = (_Float16*)(emb + 786432);     // 786432 f
    _Float16* giTb  = giTa + 1572864;                // 786432 f
    _Float16* gpa   = giTb + 1572864;                // 786432 f
    _Float16* gpb   = gpa  + 1572864;                // 786432 f
    float* pre      = (float*)(gpb + 1572864);       // 129024
    float* alpha    = pre   + 129024;                // 129024
    _Float16* wfa   = (_Float16*)(alpha + 129024);   // 98304 f
    _Float16* wfb   = wfa + 196608;                  // 98304 f
    _Float16* bwf   = wfb + 196608;                  // 32768 f
    _Float16* mf    = bwf + 65536;                   // 32768 f
    _Float16* xh    = mf  + 65536;                   // 262144 f
    _Float16* hU    = xh  + 524288;                  // 8257536 f

    const int GRU_LDS = 98304 + 16384 + 1024;        // 115712 B
    (void)hipFuncSetAttribute((const void*)k_gru_f,
                              hipFuncAttributeMaxDynamicSharedMemorySize, GRU_LDS);
    const int B2_LDS = 65536 + 256 + 64;
    (void)hipFuncSetAttribute((const void*)k_beta2,
                              hipFuncAttributeMaxDynamicSharedMemorySize, B2_LDS);
    const int W2_LDS = 65536;
    (void)hipFuncSetAttribute((const void*)k_wout2,
                              hipFuncAttributeMaxDynamicSharedMemorySize, W2_LDS);

    k_emb<<<2048, 256, 0, stream>>>(x, emb_w, emb_b, out_w, emb, ewh);
    k_gates<<<256, 256, 0, stream>>>(emb, a_wih, a_bih, a_bhh, b_wih, b_bih, b_bhh, giTa, giTb);
    k_wfrag<<<384, 64, 0, stream>>>(a_whh, wfa, 1.0f);
    k_wfrag<<<384, 64, 0, stream>>>(b_whh, wfb, 1.0f);
    k_wfrag<<<128, 64, 0, stream>>>(beta_w, bwf, 0.5f);
    k_mfrag<<<128, 64, 0, stream>>>(emb_w, out_w, mf);
    k_xh<<<2048, 256, 0, stream>>>(x, xh);
    k_gipack<<<256, 512, 0, stream>>>(giTa, giTb, gpa, gpb);
    k_gru_f<<<252, 512, GRU_LDS, stream>>>(gpa, gpb, wfa, wfb, a_bhh, b_bhh,
                                           alpha_w, alpha_b, pre, hU);
    k_softmax<<<2016, 64, 0, stream>>>(pre, alpha);
    k_beta2<<<252, 256, B2_LDS, stream>>>(hU, bwf, beta_b, alpha, ewh, out_b, out);
    k_wout2<<<252, 256, W2_LDS, stream>>>(hU, mf, xh, out);
}

// Round 9
// 325.577 us; speedup vs baseline: 3.5092x; 1.3641x over previous
//
#include <hip/hip_runtime.h>
#include <math.h>

// Problem constants: B=32, T=64, I=E=Ha=Hb=256, O=1, P=T-1=63
#define B_   32
#define T_   64
#define P_   63
#define E_   256

typedef _Float16 half8 __attribute__((ext_vector_type(8)));
typedef _Float16 half4 __attribute__((ext_vector_type(4)));
typedef float    f32x4 __attribute__((ext_vector_type(4)));

__device__ __forceinline__ float sigmoidf_(float x) { return 1.0f / (1.0f + __expf(-x)); }
__device__ __forceinline__ float tanhfast_(float x) { float e = __expf(2.0f*x); return 1.0f - 2.0f/(e + 1.0f); }

// Barrier WITHOUT vmcnt drain: only LDS ops must be visible across it.
__device__ __forceinline__ void barrier_lds_() {
    asm volatile("" ::: "memory");
    asm volatile("s_waitcnt lgkmcnt(0)" ::: "memory");
    __builtin_amdgcn_s_barrier();
    asm volatile("" ::: "memory");
}

// ---------------------------------------------------------------- K_prep: all weight->fp16 MFMA A-fragments, one launch.
// frag layout: dst[(r*64 + l)*8 + j], r = ot*8+kc, value = scale*W[ot*16+(l&15)][kc*32+(l>>4)*8+j]
__global__ __launch_bounds__(64) void k_prep(
    const float* __restrict__ awhh, const float* __restrict__ bwhh,
    const float* __restrict__ awih, const float* __restrict__ bwih,
    const float* __restrict__ beta_w, const float* __restrict__ emb_w, const float* __restrict__ out_w,
    _Float16* __restrict__ wfa, _Float16* __restrict__ wfb,
    _Float16* __restrict__ wifa, _Float16* __restrict__ wifb,
    _Float16* __restrict__ bwf, _Float16* __restrict__ mf)
{
    int bid = blockIdx.x, l = threadIdx.x;
    if (bid < 1664) {
        const float* W; _Float16* dst; float scale = 1.0f; int r;
        if (bid < 384)       { W = awhh;   dst = wfa;  r = bid; }
        else if (bid < 768)  { W = bwhh;   dst = wfb;  r = bid - 384; }
        else if (bid < 1152) { W = awih;   dst = wifa; r = bid - 768; }
        else if (bid < 1536) { W = bwih;   dst = wifb; r = bid - 1152; }
        else                 { W = beta_w; dst = bwf;  r = bid - 1536; scale = 0.5f; }
        int ot = r >> 3, kc = r & 7;
        int orow = ot * 16 + (l & 15);
        int c0   = kc * 32 + (l >> 4) * 8;
        half8 v;
        #pragma unroll
        for (int j = 0; j < 8; ++j) v[j] = (_Float16)(scale * W[(size_t)orow * 256 + c0 + j]);
        *reinterpret_cast<half8*>(&dst[((size_t)r * 64 + l) * 8]) = v;
    } else {
        int r = bid - 1664;     // M^T frags: A[row=i][k=e] = out_w[e]*emb_w[e][i]
        int ot = r >> 3, kc = r & 7;
        int i  = ot * 16 + (l & 15);
        int e0 = kc * 32 + (l >> 4) * 8;
        half8 v;
        #pragma unroll
        for (int j = 0; j < 8; ++j) v[j] = (_Float16)(out_w[e0 + j] * emb_w[(size_t)(e0 + j) * 256 + i]);
        *reinterpret_cast<half8*>(&mf[((size_t)r * 64 + l) * 8]) = v;
    }
}

// ---------------------------------------------------------------- K1: emb (8 rows/block) -> embh, ewh, xh (all fp16)
__global__ __launch_bounds__(256) void k_emb(const float* __restrict__ x,
                                             const float* __restrict__ emb_w,
                                             const float* __restrict__ emb_b,
                                             const float* __restrict__ out_w,
                                             _Float16* __restrict__ embh,
                                             _Float16* __restrict__ ewh,
                                             _Float16* __restrict__ xh) {
    int r0 = blockIdx.x * 8;       // row = t*32 + b
    int tid = threadIdx.x;
    __shared__ float xs[8][E_];
    for (int rr = 0; rr < 8; ++rr) {
        int row = r0 + rr, t = row >> 5, b = row & 31;
        float xv = x[((size_t)b * T_ + t) * E_ + tid];
        xs[rr][tid] = xv;
        xh[((size_t)b * T_ + t) * E_ + tid] = (_Float16)xv;
    }
    __syncthreads();
    float acc[8];
    #pragma unroll
    for (int rr = 0; rr < 8; ++rr) acc[rr] = 0.f;
    const float* wr = emb_w + (size_t)tid * E_;
    for (int c = 0; c < 256; c += 4) {
        float4 wv = *reinterpret_cast<const float4*>(wr + c);
        #pragma unroll
        for (int rr = 0; rr < 8; ++rr) {
            float4 ev = *reinterpret_cast<const float4*>(&xs[rr][c]);
            acc[rr] += wv.x * ev.x + wv.y * ev.y + wv.z * ev.z + wv.w * ev.w;
        }
    }
    float eb = emb_b[tid], ow = out_w[tid];
    #pragma unroll
    for (int rr = 0; rr < 8; ++rr) {
        float v = acc[rr] + eb;
        embh[(size_t)(r0 + rr) * E_ + tid] = (_Float16)v;
        ewh[(size_t)(r0 + rr) * E_ + tid]  = (_Float16)(v * ow);
    }
}

// ---------------------------------------------------------------- K2: gi = wih @ emb^T + bias via MFMA, written DIRECTLY in
// gp packed layout (the MFMA D-fragment IS the pack order). block=(g,t): 128 blocks x 512 thr.
// gp[(((t*2+bh)*8+w)*3+g3)*512 + l*8 + e], e=i*4+j -> dim 32w+16i+lg*4+j, batch bh*16+lr.
// b_ih folded always; b_hh folded for r,z gates (n-gate's b_hh added in k_gru_f).
__global__ __launch_bounds__(512, 2) void k_gates2(
    const _Float16* __restrict__ embh,
    const _Float16* __restrict__ wifa, const _Float16* __restrict__ wifb,
    const float* __restrict__ abih, const float* __restrict__ abhh,
    const float* __restrict__ bbih, const float* __restrict__ bbhh,
    _Float16* __restrict__ gpa, _Float16* __restrict__ gpb)
{
    __shared__ _Float16 esw[32 * E_];   // 16 KB swizzled emb rows (batch) for this t
    int bid = blockIdx.x;
    int g = bid >> 6, t = bid & 63;
    const _Float16* wif = g ? wifb : wifa;
    const float* bih = g ? bbih : abih;
    const float* bhh = g ? bbhh : abhh;
    _Float16* gp = g ? gpb : gpa;
    int tid = threadIdx.x, w = tid >> 6, l = tid & 63, lg = l >> 4, lr = l & 15;

    #pragma unroll
    for (int q = 0; q < 2; ++q) {
        int idx = q * 512 + tid;         // half8 index: 32 rows x 32 chunks
        int b = idx >> 5, e0 = (idx & 31) * 8;
        half8 v = *reinterpret_cast<const half8*>(&embh[((size_t)t * 32 + b) * E_ + e0]);
        *reinterpret_cast<half8*>(&esw[b * E_ + (e0 ^ ((b & 7) << 3))]) = v;
    }
    // A-frags (wih) for this wave's 32 dims x 3 gates
    half8 aw[3][2][8];
    #pragma unroll
    for (int g3 = 0; g3 < 3; ++g3)
        #pragma unroll
        for (int i = 0; i < 2; ++i)
            #pragma unroll
            for (int kc = 0; kc < 8; ++kc)
                aw[g3][i][kc] = *reinterpret_cast<const half8*>(
                    &wif[(((size_t)(g3 * 16 + 2 * w + i) * 8 + kc) * 64 + l) * 8]);
    f32x4 acc[3][2][2];
    #pragma unroll
    for (int g3 = 0; g3 < 3; ++g3)
        #pragma unroll
        for (int i = 0; i < 2; ++i)
            #pragma unroll
            for (int rt = 0; rt < 2; ++rt)
                #pragma unroll
                for (int j = 0; j < 4; ++j) {
                    int d = g3 * 256 + 32 * w + 16 * i + lg * 4 + j;
                    acc[g3][i][rt][j] = bih[d] + ((g3 < 2) ? bhh[d] : 0.f);
                }
    __syncthreads();
    #pragma unroll
    for (int kc = 0; kc < 8; ++kc) {
        half8 eb[2];
        #pragma unroll
        for (int rt = 0; rt < 2; ++rt)
            eb[rt] = *reinterpret_cast<const half8*>(
                &esw[(rt * 16 + lr) * E_ + ((kc * 32 + lg * 8) ^ ((lr & 7) << 3))]);
        #pragma unroll
        for (int g3 = 0; g3 < 3; ++g3)
            #pragma unroll
            for (int i = 0; i < 2; ++i)
                #pragma unroll
                for (int rt = 0; rt < 2; ++rt)
                    acc[g3][i][rt] = __builtin_amdgcn_mfma_f32_16x16x32_f16(
                        aw[g3][i][kc], eb[rt], acc[g3][i][rt], 0, 0, 0);
    }
    #pragma unroll
    for (int g3 = 0; g3 < 3; ++g3)
        #pragma unroll
        for (int rt = 0; rt < 2; ++rt) {
            half8 v;
            #pragma unroll
            for (int i = 0; i < 2; ++i)
                #pragma unroll
                for (int j = 0; j < 4; ++j) v[i * 4 + j] = (_Float16)acc[g3][i][rt][j];
            *reinterpret_cast<half8*>(
                &gp[((((size_t)t * 2 + rt) * 8 + w) * 3 + g3) * 512 + l * 8]) = v;
        }
}

// ---------------------------------------------------------------- K3: triangular GRU chains (R8 version, unchanged).
__global__ __launch_bounds__(512, 2) void k_gru_f(
    const _Float16* __restrict__ gpa, const _Float16* __restrict__ gpb,
    const _Float16* __restrict__ wfa, const _Float16* __restrict__ wfb,
    const float* __restrict__ abhh, const float* __restrict__ bbhh,
    const float* __restrict__ alpha_w, const float* __restrict__ alpha_b,
    float* __restrict__ pre, _Float16* __restrict__ hstore)
{
    extern __shared__ char smem[];
    half8*    wlds = reinterpret_cast<half8*>(smem);              // 96 KB
    _Float16* hsp  = reinterpret_cast<_Float16*>(smem + 98304);   // 16 KB
    float*    red  = reinterpret_cast<float*>(smem + 98304 + 16384);  // [2][16][8]

    int bid = blockIdx.x;
    int p   = 62 - (bid >> 2);
    int g   = (bid >> 1) & 1;
    int bh  = bid & 1;
    int tid = threadIdx.x;
    int w = tid >> 6, l = tid & 63, lg = l >> 4, lr = l & 15;
    const _Float16* gp  = g ? gpb : gpa;
    const _Float16* wf  = g ? wfb : wfa;
    const float*    bhh = g ? bbhh : abhh;

    half8 wreg[3][2][6];
    #pragma unroll
    for (int g3 = 0; g3 < 3; ++g3)
        #pragma unroll
        for (int i = 0; i < 2; ++i) {
            int ot = g3 * 16 + 2 * w + i;
            #pragma unroll
            for (int kc = 0; kc < 6; ++kc)
                wreg[g3][i][kc] = *reinterpret_cast<const half8*>(&wf[((size_t)(ot * 8 + kc) * 64 + l) * 8]);
        }
    #pragma unroll
    for (int q = 0; q < 12; ++q) {
        int idx = q * 512 + tid;
        int ot = idx >> 7, kcs = (idx >> 6) & 1, l2 = idx & 63;
        wlds[idx] = *reinterpret_cast<const half8*>(&wf[((size_t)(ot * 8 + 6 + kcs) * 64 + l2) * 8]);
    }
    float bhn[2][4], awv[2][4];
    #pragma unroll
    for (int i = 0; i < 2; ++i)
        #pragma unroll
        for (int j = 0; j < 4; ++j) {
            int d = 32 * w + 16 * i + lg * 4 + j;
            bhn[i][j] = bhh[512 + d];
            awv[i][j] = alpha_w[d];
        }
    float ab = alpha_b[0];
    float hreg[2][4];
    #pragma unroll
    for (int i = 0; i < 2; ++i)
        #pragma unroll
        for (int j = 0; j < 4; ++j) hreg[i][j] = 0.f;
    __syncthreads();

    size_t tri = (size_t)p * (p + 1) / 2;

    for (int k = 0; k <= p; ++k) {
        int t_in = p - k;
        int wr = k & 1, rb = wr ^ 1;
        if (k > 0 && g == 0 && tid < 16) {
            float s = 0.f;
            #pragma unroll
            for (int q = 0; q < 8; ++q) s += red[(rb * 16 + tid) * 8 + q];
            pre[((size_t)p * T_ + (t_in + 1)) * B_ + bh * 16 + tid] = 0.5f * s + ab;
        }
        half8 gch[3];
        {
            const _Float16* gq = gp + (((size_t)(t_in * 2 + bh) * 8 + w) * 3) * 512 + l * 8;
            #pragma unroll
            for (int c = 0; c < 3; ++c)
                gch[c] = *reinterpret_cast<const half8*>(gq + (size_t)c * 512);
        }
        f32x4 acc[3][2];
        #pragma unroll
        for (int g3 = 0; g3 < 3; ++g3)
            #pragma unroll
            for (int i = 0; i < 2; ++i)
                #pragma unroll
                for (int j = 0; j < 4; ++j) acc[g3][i][j] = 0.f;
        if (k > 0) {
            half8 bhv[2];
            {
                int cb = (lg * 8) ^ ((lr & 7) << 3);
                bhv[0] = *reinterpret_cast<const half8*>(&hsp[(rb * 16 + lr) * 256 + cb]);
            }
            #pragma unroll
            for (int kc = 0; kc < 8; ++kc) {
                if (kc < 7) {
                    int cb = ((kc + 1) * 32 + lg * 8) ^ ((lr & 7) << 3);
                    bhv[(kc + 1) & 1] = *reinterpret_cast<const half8*>(&hsp[(rb * 16 + lr) * 256 + cb]);
                }
                if (kc < 6) {
                    #pragma unroll
                    for (int g3 = 0; g3 < 3; ++g3)
                        #pragma unroll
                        for (int i = 0; i < 2; ++i)
                            acc[g3][i] = __builtin_amdgcn_mfma_f32_16x16x32_f16(
                                wreg[g3][i][kc], bhv[kc & 1], acc[g3][i], 0, 0, 0);
                } else {
                    #pragma unroll
                    for (int g3 = 0; g3 < 3; ++g3)
                        #pragma unroll
                        for (int i = 0; i < 2; ++i) {
                            half8 wlv = wlds[((g3 * 16 + 2 * w + i) * 2 + (kc - 6)) * 64 + l];
                            acc[g3][i] = __builtin_amdgcn_mfma_f32_16x16x32_f16(
                                wlv, bhv[kc & 1], acc[g3][i], 0, 0, 0);
                        }
                }
            }
        }
        _Float16* hdst = hstore + ((tri + (size_t)k) * B_ + bh * 16 + lr) * (size_t)E_ + 32 * w + lg * 4;
        #pragma unroll
        for (int i = 0; i < 2; ++i) {
            half4 hh;
            #pragma unroll
            for (int j = 0; j < 4; ++j) {
                int e = i * 4 + j;
                float rg = sigmoidf_(acc[0][i][j] + (float)gch[0][e]);
                float zg = sigmoidf_(acc[1][i][j] + (float)gch[1][e]);
                float ng = tanhfast_((float)gch[2][e] + rg * (acc[2][i][j] + bhn[i][j]));
                float h  = (1.f - zg) * ng + zg * hreg[i][j];
                hreg[i][j] = h;
                hh[j] = (_Float16)h;
            }
            int ce = (32 * w + 16 * i + lg * 4) ^ ((lr & 7) << 3);
            *reinterpret_cast<half4*>(&hsp[(wr * 16 + lr) * 256 + ce]) = hh;
            if (g) *reinterpret_cast<half4*>(hdst + 16 * i) = hh;
        }
        if (!g) {
            float pa = 0.f;
            #pragma unroll
            for (int i = 0; i < 2; ++i)
                #pragma unroll
                for (int j = 0; j < 4; ++j) pa += hreg[i][j] * awv[i][j];
            pa += __shfl_xor(pa, 16, 64);
            pa += __shfl_xor(pa, 32, 64);
            if (l < 16) red[(wr * 16 + l) * 8 + w] = pa;
        }
        barrier_lds_();
    }
    if (g == 0 && tid < 16) {
        int wl = p & 1;
        float s = 0.f;
        #pragma unroll
        for (int q = 0; q < 8; ++q) s += red[(wl * 16 + tid) * 8 + q];
        pre[((size_t)p * T_ + 0) * B_ + bh * 16 + tid] = 0.5f * s + ab;
    }
}

// ---------------------------------------------------------------- K5: fused attention tail. Per (p,b) pair:
// softmax(pre) -> alpha; GEMM1 beta=tanh(H@(0.5 beta_w)^T+b), U=alpha*beta (U handed to
// GEMM2 through LDS, never hits global); pred = sum U*ewh; GEMM2 G=U@M; weight = sum_k G*x/(p+1).
__global__ __launch_bounds__(256, 1) void k_att(
    const _Float16* __restrict__ hH,
    const _Float16* __restrict__ bwf, const _Float16* __restrict__ mf,
    const float* __restrict__ beta_b,
    const float* __restrict__ pre,
    const _Float16* __restrict__ ewh, const _Float16* __restrict__ xh,
    const float* __restrict__ out_b,
    float* __restrict__ out)
{
    extern __shared__ char smem[];
    _Float16* hs   = reinterpret_cast<_Float16*>(smem);            // [64][256] swz: H then U
    _Float16* es   = reinterpret_cast<_Float16*>(smem + 32768);    // [64][256] swz: ewh
    _Float16* xs   = reinterpret_cast<_Float16*>(smem + 65536);    // [64][256] swz: x
    float*    alds = reinterpret_cast<float*>(smem + 98304);       // [64]
    float*    red  = reinterpret_cast<float*>(smem + 98304 + 256); // [4]
    int tid = threadIdx.x, w = tid >> 6, l = tid & 63, lg = l >> 4, lr = l & 15;

    half8 aw[4][8], am[4][8];
    #pragma unroll
    for (int ot = 0; ot < 4; ++ot)
        #pragma unroll
        for (int kc = 0; kc < 8; ++kc) {
            size_t fo = (((size_t)(4 * w + ot) * 8 + kc) * 64 + l) * 8;
            aw[ot][kc] = *reinterpret_cast<const half8*>(&bwf[fo]);
            am[ot][kc] = *reinterpret_cast<const half8*>(&mf[fo]);
        }
    float bb[4][4];
    #pragma unroll
    for (int ot = 0; ot < 4; ++ot)
        #pragma unroll
        for (int j = 0; j < 4; ++j)
            bb[ot][j] = beta_b[(4 * w + ot) * 16 + lg * 4 + j];
    float ob = out_b[0];

    for (int it = 0; it < 8; ++it) {
        int pair = blockIdx.x * 8 + it;
        int p = pair >> 5, b = pair & 31;
        size_t tri = (size_t)p * (p + 1) / 2;
        // ---- stage H (reversed), ewh, x
        {
            int kr = tid >> 5, l32 = tid & 31, e0 = l32 * 8;
            #pragma unroll
            for (int q = 0; q < 8; ++q) {
                int k = q * 8 + kr;
                int sw = e0 ^ ((k & 7) << 3);
                half8 hv, ev;
                if (k <= p) {
                    hv = *reinterpret_cast<const half8*>(&hH[((tri + (size_t)(p - k)) * B_ + b) * 256 + e0]);
                    ev = *reinterpret_cast<const half8*>(&ewh[((size_t)k * B_ + b) * 256 + e0]);
                } else {
                    #pragma unroll
                    for (int j = 0; j < 8; ++j) { hv[j] = (_Float16)0.f; ev[j] = (_Float16)0.f; }
                }
                *reinterpret_cast<half8*>(&hs[k * 256 + sw]) = hv;
                *reinterpret_cast<half8*>(&es[k * 256 + sw]) = ev;
                *reinterpret_cast<half8*>(&xs[k * 256 + sw]) =
                    *reinterpret_cast<const half8*>(&xh[((size_t)b * T_ + k) * 256 + e0]);
            }
        }
        // ---- softmax on wave 0
        if (tid < 64) {
            float v = (tid <= p) ? pre[((size_t)p * T_ + tid) * B_ + b] : -3.4e38f;
            float m = v;
            #pragma unroll
            for (int off = 32; off > 0; off >>= 1) m = fmaxf(m, __shfl_xor(m, off, 64));
            float e = (tid <= p) ? __expf(v - m) : 0.f;
            float s = e;
            #pragma unroll
            for (int off = 32; off > 0; off >>= 1) s += __shfl_xor(s, off, 64);
            alds[tid] = e / s;
        }
        __syncthreads();
        // ---- GEMM1: beta pre-activations
        f32x4 acc[4][4];
        #pragma unroll
        for (int ot = 0; ot < 4; ++ot)
            #pragma unroll
            for (int rt = 0; rt < 4; ++rt)
                #pragma unroll
                for (int j = 0; j < 4; ++j) acc[ot][rt][j] = bb[ot][j];
        #pragma unroll
        for (int kc = 0; kc < 8; ++kc) {
            half8 hb[4];
            #pragma unroll
            for (int rt = 0; rt < 4; ++rt)
                hb[rt] = *reinterpret_cast<const half8*>(&hs[(rt * 16 + lr) * 256 + ((kc * 32 + lg * 8) ^ ((lr & 7) << 3))]);
            #pragma unroll
            for (int ot = 0; ot < 4; ++ot)
                #pragma unroll
                for (int rt = 0; rt < 4; ++rt)
                    acc[ot][rt] = __builtin_amdgcn_mfma_f32_16x16x32_f16(aw[ot][kc], hb[rt], acc[ot][rt], 0, 0, 0);
        }
        // ---- epilogue1: U (registers) + pred partial
        float pv = 0.f;
        half4 ureg[4][4];
        #pragma unroll
        for (int ot = 0; ot < 4; ++ot)
            #pragma unroll
            for (int rt = 0; rt < 4; ++rt) {
                int k = rt * 16 + lr;
                float al = alds[k];
                int d0 = (4 * w + ot) * 16 + lg * 4;
                half4 ev4 = *reinterpret_cast<const half4*>(&es[k * 256 + (d0 ^ ((lr & 7) << 3))]);
                #pragma unroll
                for (int j = 0; j < 4; ++j) {
                    float u = al * tanhfast_(acc[ot][rt][j]);
                    ureg[ot][rt][j] = (_Float16)u;
                    pv += u * (float)ev4[j];
                }
            }
        __syncthreads();   // all hs/es reads done
        // ---- U -> hs (overwrite H in place), pred partials -> red
        #pragma unroll
        for (int ot = 0; ot < 4; ++ot)
            #pragma unroll
            for (int rt = 0; rt < 4; ++rt) {
                int k = rt * 16 + lr;
                int d0 = (4 * w + ot) * 16 + lg * 4;
                *reinterpret_cast<half4*>(&hs[k * 256 + (d0 ^ ((lr & 7) << 3))]) = ureg[ot][rt];
            }
        #pragma unroll
        for (int off = 1; off < 64; off <<= 1) pv += __shfl_xor(pv, off, 64);
        if (l == 0) red[w] = pv;
        __syncthreads();   // U visible + red visible
        if (tid == 0) out[(size_t)b * P_ + p] = red[0] + red[1] + red[2] + red[3] + ob;
        // ---- GEMM2: G = U @ M
        f32x4 a2[4][4];
        #pragma unroll
        for (int ot = 0; ot < 4; ++ot)
            #pragma unroll
            for (int rt = 0; rt < 4; ++rt)
                #pragma unroll
                for (int j = 0; j < 4; ++j) a2[ot][rt][j] = 0.f;
        #pragma unroll
        for (int kc = 0; kc < 8; ++kc) {
            half8 ub[4];
            #pragma unroll
            for (int rt = 0; rt < 4; ++rt)
                ub[rt] = *reinterpret_cast<const half8*>(&hs[(rt * 16 + lr) * 256 + ((kc * 32 + lg * 8) ^ ((lr & 7) << 3))]);
            #pragma unroll
            for (int ot = 0; ot < 4; ++ot)
                #pragma unroll
                for (int rt = 0; rt < 4; ++rt)
                    a2[ot][rt] = __builtin_amdgcn_mfma_f32_16x16x32_f16(am[ot][kc], ub[rt], a2[ot][rt], 0, 0, 0);
        }
        // ---- epilogue2: weight = sum_k G*x /(p+1)
        float r4[4][4];
        #pragma unroll
        for (int ot = 0; ot < 4; ++ot)
            #pragma unroll
            for (int j = 0; j < 4; ++j) r4[ot][j] = 0.f;
        #pragma unroll
        for (int ot = 0; ot < 4; ++ot)
            #pragma unroll
            for (int rt = 0; rt < 4; ++rt) {
                int k = rt * 16 + lr;
                int i0 = (4 * w + ot) * 16 + lg * 4;
                half4 xv4 = *reinterpret_cast<const half4*>(&xs[k * 256 + (i0 ^ ((lr & 7) << 3))]);
                #pragma unroll
                for (int j = 0; j < 4; ++j) r4[ot][j] += a2[ot][rt][j] * (float)xv4[j];
            }
        #pragma unroll
        for (int off = 1; off < 16; off <<= 1)
            #pragma unroll
            for (int ot = 0; ot < 4; ++ot)
                #pragma unroll
                for (int j = 0; j < 4; ++j) r4[ot][j] += __shfl_xor(r4[ot][j], off, 64);
        if (lr == 0) {
            float inv = 1.f / (float)(p + 1);
            #pragma unroll
            for (int ot = 0; ot < 4; ++ot) {
                f32x4 v;
                #pragma unroll
                for (int j = 0; j < 4; ++j) v[j] = r4[ot][j] * inv;
                *reinterpret_cast<f32x4*>(&out[2016 + ((size_t)b * P_ + p) * 256 + (4 * w + ot) * 16 + lg * 4]) = v;
            }
        }
        __syncthreads();   // before next pair's staging
    }
}

// ---------------------------------------------------------------- host
extern "C" void kernel_launch(void* const* d_in, const int* in_sizes, int n_in,
                              void* d_out, int out_size, void* d_ws, size_t ws_size,
                              hipStream_t stream) {
    const float* x       = (const float*)d_in[0];
    const float* emb_w   = (const float*)d_in[1];
    const float* emb_b   = (const float*)d_in[2];
    const float* a_wih   = (const float*)d_in[3];
    const float* a_whh   = (const float*)d_in[4];
    const float* a_bih   = (const float*)d_in[5];
    const float* a_bhh   = (const float*)d_in[6];
    const float* b_wih   = (const float*)d_in[7];
    const float* b_whh   = (const float*)d_in[8];
    const float* b_bih   = (const float*)d_in[9];
    const float* b_bhh   = (const float*)d_in[10];
    const float* alpha_w = (const float*)d_in[11];
    const float* alpha_b = (const float*)d_in[12];
    const float* beta_w  = (const float*)d_in[13];
    const float* beta_b  = (const float*)d_in[14];
    const float* out_w   = (const float*)d_in[15];
    const float* out_b   = (const float*)d_in[16];
    float* out = (float*)d_out;

    float* ws = (float*)d_ws;
    // ws layout (floats), total ~11.2M floats = 44.8 MB
    _Float16* embh = (_Float16*)ws;                  // 524288 h = 262144 f
    _Float16* ewh  = embh + 524288;                  // 262144 f
    _Float16* xh   = ewh  + 524288;                  // 262144 f
    _Float16* gpa  = xh   + 524288;                  // 1572864 h = 786432 f
    _Float16* gpb  = gpa  + 1572864;                 // 786432 f
    float* pre     = (float*)(gpb + 1572864);        // 129024 f
    _Float16* wfa  = (_Float16*)(pre + 129024);      // 196608 h = 98304 f
    _Float16* wfb  = wfa + 196608;                   // 98304 f
    _Float16* wifa = wfb + 196608;                   // 98304 f
    _Float16* wifb = wifa + 196608;                  // 98304 f
    _Float16* bwf  = wifb + 196608;                  // 65536 h = 32768 f
    _Float16* mf   = bwf + 65536;                    // 32768 f
    _Float16* hH   = mf  + 65536;                    // 16515072 h = 8257536 f

    const int GRU_LDS = 98304 + 16384 + 1024;        // 115712 B
    (void)hipFuncSetAttribute((const void*)k_gru_f,
                              hipFuncAttributeMaxDynamicSharedMemorySize, GRU_LDS);
    const int ATT_LDS = 98304 + 256 + 64;            // 98624 B
    (void)hipFuncSetAttribute((const void*)k_att,
                              hipFuncAttributeMaxDynamicSharedMemorySize, ATT_LDS);

    k_prep<<<1792, 64, 0, stream>>>(a_whh, b_whh, a_wih, b_wih, beta_w, emb_w, out_w,
                                    wfa, wfb, wifa, wifb, bwf, mf);
    k_emb<<<256, 256, 0, stream>>>(x, emb_w, emb_b, out_w, embh, ewh, xh);
    k_gates2<<<128, 512, 0, stream>>>(embh, wifa, wifb, a_bih, a_bhh, b_bih, b_bhh, gpa, gpb);
    k_gru_f<<<252, 512, GRU_LDS, stream>>>(gpa, gpb, wfa, wfb, a_bhh, b_bhh,
                                           alpha_w, alpha_b, pre, hH);
    k_att<<<252, 256, ATT_LDS, stream>>>(hH, bwf, mf, beta_b, pre, ewh, xh, out_b, out);
}